// Round 3
// baseline (379.167 us; speedup 1.0000x reference)
//
#include <hip/hip_runtime.h>
#include <hip/hip_bf16.h>

#define NPTS 8192
#define DIM  512
#define NHEAD 8
#define HDIM 64

typedef short bf16x8 __attribute__((ext_vector_type(8)));   // 8 bf16 = 4 VGPRs
typedef float f32x4  __attribute__((ext_vector_type(4)));   // MFMA C/D

#define GLOBAL_AS __attribute__((address_space(1)))
#define LDS_AS    __attribute__((address_space(3)))

#if __has_builtin(__builtin_amdgcn_exp2f)
#define EXP2F(x) __builtin_amdgcn_exp2f(x)
#else
#define EXP2F(x) __expf((x) * 0.6931471805599453f)
#endif

// fp32 -> bf16 round-nearest-even (scalar)
__device__ __forceinline__ unsigned short f2bf(float f) {
    union { float f; unsigned int u; } v; v.f = f;
    unsigned int r = v.u + 0x7FFFu + ((v.u >> 16) & 1u);
    return (unsigned short)(r >> 16);
}
__device__ __forceinline__ float bf2f(unsigned short u) {
    union { unsigned int i; float f; } v; v.i = ((unsigned int)u) << 16;
    return v.f;
}
// packed 2x f32 -> bf16 pair (v_cvt_pk_bf16_f32 on gfx950)
__device__ __forceinline__ unsigned int pk2bf(float a, float b) {
    __hip_bfloat162 h = __float22bfloat162_rn(float2{a, b});
    union { __hip_bfloat162 h; unsigned int u; } v; v.h = h;
    return v.u;
}

// ---------------------------------------------------------------------------
// Prep 1: x fp32 -> bf16
// ---------------------------------------------------------------------------
__global__ __launch_bounds__(256) void cvt_x_kernel(
    const float* __restrict__ in, unsigned short* __restrict__ outp)
{
    int gid = blockIdx.x * 256 + threadIdx.x;   // over N*DIM/8
    float4 a = ((const float4*)in)[gid * 2];
    float4 b = ((const float4*)in)[gid * 2 + 1];
    uint4 u;
    u.x = pk2bf(a.x, a.y); u.y = pk2bf(a.z, a.w);
    u.z = pk2bf(b.x, b.y); u.w = pk2bf(b.z, b.w);
    ((uint4*)outp)[gid] = u;
}

// ---------------------------------------------------------------------------
// Prep 2: Wq/Wk/Wv [h][512][64] fp32 -> wtq [zh][64][512] bf16 (transposed)
// ---------------------------------------------------------------------------
__global__ __launch_bounds__(256) void tr_w_kernel(
    const float* __restrict__ Wq, const float* __restrict__ Wk,
    const float* __restrict__ Wv, unsigned short* __restrict__ wtq)
{
    int zh = blockIdx.z, z = zh >> 3, h = zh & 7;
    const float* src = (z == 0 ? Wq : z == 1 ? Wk : Wv) + (size_t)h * DIM * HDIM;
    unsigned short* dst = wtq + (size_t)zh * HDIM * DIM;
    int k0 = blockIdx.x * 64;
    __shared__ float tile[64][65];
    int t = threadIdx.x, c = t & 63, r = t >> 6;
    #pragma unroll
    for (int i = 0; i < 16; ++i)
        tile[r + 4 * i][c] = src[(size_t)(k0 + r + 4 * i) * HDIM + c];
    __syncthreads();
    #pragma unroll
    for (int i = 0; i < 16; ++i)
        dst[(size_t)(r + 4 * i) * DIM + k0 + c] = f2bf(tile[c][r + 4 * i]);
}

// ---------------------------------------------------------------------------
// Prep 3: Wo [512][512] fp32 -> wot [512][512] bf16 transposed ([e_out][k])
// ---------------------------------------------------------------------------
__global__ __launch_bounds__(256) void tr_wo_kernel(
    const float* __restrict__ Wo, unsigned short* __restrict__ wot)
{
    int k0 = blockIdx.x * 64, e0 = blockIdx.y * 64;
    __shared__ float tile[64][65];
    int t = threadIdx.x, c = t & 63, r = t >> 6;
    #pragma unroll
    for (int i = 0; i < 16; ++i)
        tile[r + 4 * i][c] = Wo[(size_t)(k0 + r + 4 * i) * DIM + e0 + c];
    __syncthreads();
    #pragma unroll
    for (int i = 0; i < 16; ++i)
        wot[(size_t)(e0 + r + 4 * i) * DIM + k0 + c] = f2bf(tile[c][r + 4 * i]);
}

// ---------------------------------------------------------------------------
// QKV projection, bf16 MFMA, direct-global frags.
//   z=0: q_bf[h][n][e]  (scale*log2e folded)   z=1: k_bf[h][n][e]
//   z=2: vtp[h][e][pi(n)] = V^T with the PV sigma-permutation pre-applied
//        within each 32-key block (pos = 8*quad + 4*mt + r holds
//        key = 16*mt + 4*quad + r) -- matches P^T's B-frag key order.
// ---------------------------------------------------------------------------
__global__ __launch_bounds__(256) void qkv_mfma_kernel(
    const unsigned short* __restrict__ xbf,   // [N][512] bf16
    const unsigned short* __restrict__ wtq,   // [24][64][512] bf16
    const float* __restrict__ bq, const float* __restrict__ bk,
    const float* __restrict__ bv,
    unsigned short* __restrict__ q_bf, unsigned short* __restrict__ k_bf,
    unsigned short* __restrict__ vt_bf)
{
    const int zh = blockIdx.y, z = zh >> 3, h = zh & 7;
    const unsigned short* W = wtq + (size_t)zh * HDIM * DIM;
    const float* b = (z == 0 ? bq : z == 1 ? bk : bv) + h * HDIM;
    const int t = threadIdx.x, w = t >> 6, lane = t & 63;
    const int l15 = lane & 15, quad = lane >> 4;
    const int r0 = blockIdx.x * 128 + w * 32;

    f32x4 O[2][4];
    #pragma unroll
    for (int mt = 0; mt < 2; ++mt)
        #pragma unroll
        for (int tn = 0; tn < 4; ++tn) O[mt][tn] = (f32x4){0.f, 0.f, 0.f, 0.f};

    for (int k0 = 0; k0 < DIM; k0 += 64) {
        bf16x8 af[2][2], bf[4][2];
        #pragma unroll
        for (int mt = 0; mt < 2; ++mt)
            #pragma unroll
            for (int kc = 0; kc < 2; ++kc)
                af[mt][kc] = *(const bf16x8*)
                    &xbf[(size_t)(r0 + 16 * mt + l15) * DIM + k0 + quad * 8 + 32 * kc];
        #pragma unroll
        for (int tn = 0; tn < 4; ++tn)
            #pragma unroll
            for (int kc = 0; kc < 2; ++kc)
                bf[tn][kc] = *(const bf16x8*)
                    &W[(size_t)(l15 + 16 * tn) * DIM + k0 + quad * 8 + 32 * kc];
        #pragma unroll
        for (int mt = 0; mt < 2; ++mt)
            #pragma unroll
            for (int tn = 0; tn < 4; ++tn) {
                O[mt][tn] = __builtin_amdgcn_mfma_f32_16x16x32_bf16(
                    af[mt][0], bf[tn][0], O[mt][tn], 0, 0, 0);
                O[mt][tn] = __builtin_amdgcn_mfma_f32_16x16x32_bf16(
                    af[mt][1], bf[tn][1], O[mt][tn], 0, 0, 0);
            }
    }

    if (z < 2) {
        unsigned short* outp = (z == 0 ? q_bf : k_bf) + (size_t)h * NPTS * HDIM;
        const float sc = (z == 0) ? 0.18033688011112042f : 1.0f;  // 0.125*log2e | 1
        #pragma unroll
        for (int mt = 0; mt < 2; ++mt)
            #pragma unroll
            for (int tn = 0; tn < 4; ++tn) {
                int e = l15 + 16 * tn;
                float be = b[e];
                #pragma unroll
                for (int r = 0; r < 4; ++r) {
                    int n = r0 + 16 * mt + quad * 4 + r;
                    outp[(size_t)n * HDIM + e] = f2bf((O[mt][tn][r] + be) * sc);
                }
            }
    } else {
        unsigned short* vt = vt_bf + (size_t)h * HDIM * NPTS;
        #pragma unroll
        for (int mt = 0; mt < 2; ++mt)
            #pragma unroll
            for (int tn = 0; tn < 4; ++tn) {
                int e = l15 + 16 * tn;
                float be = b[e];
                uint2 pk;
                pk.x = pk2bf(O[mt][tn][0] + be, O[mt][tn][1] + be);
                pk.y = pk2bf(O[mt][tn][2] + be, O[mt][tn][3] + be);
                // sigma-permuted position within this 32-row block
                *(uint2*)&vt[(size_t)e * NPTS + r0 + quad * 8 + mt * 4] = pk;
            }
    }
}

// ---------------------------------------------------------------------------
// MFMA flash attention, R11: 64 q-rows/wave (kept from R10) with the spill
// fixed. R10 post-mortem: __launch_bounds__(256,2) made the allocator cap at
// 128 VGPR and spill ~6 regs/iter to scratch (WRITE_SIZE 17->194 MB), eating
// the LDS-amplification win. Fixes:
//   (a) plain __launch_bounds__(256) -- R9's proven-benign spec;
//   (b) QK^T split into two 32-key sub-phases per 64-key half: only
//       kf[2][2] (16 regs) + st[2][4] (32 regs) transient at a time,
//       folded immediately into pt. Live peak ~185 VGPR < 256.
// Structure otherwise identical to R10: 128-key staged tile (2x 64-key
// subtiles, same XOR chunk swizzle), double-buffered, one barrier/iter,
// V-frags loaded after softmax, max-free softmax, k-split 2.
// ---------------------------------------------------------------------------
__global__ __launch_bounds__(256) void attn_kernel(
    const unsigned short* __restrict__ qg,   // [H][N][64] bf16, pre-scaled
    const unsigned short* __restrict__ kg,   // [H][N][64] bf16
    const unsigned short* __restrict__ vtg,  // [H][64][N] bf16, sigma-permuted
    unsigned short* __restrict__ opart,      // [2][N][DIM] bf16 unnormalized
    float* __restrict__ lpart)               // [2][H][N] fp32
{
    const int h  = blockIdx.y;
    const int ks = blockIdx.z;
    const int q0 = blockIdx.x * 256;
    const int kbase = ks * (NPTS / 2);
    const unsigned short* Q  = qg  + (size_t)h * NPTS * HDIM;
    const unsigned short* K  = kg  + (size_t)h * NPTS * HDIM;
    const unsigned short* Vt = vtg + (size_t)h * HDIM * NPTS;
    unsigned short* op = opart + (size_t)ks * NPTS * DIM;
    float* lp = lpart + (size_t)(ks * NHEAD + h) * NPTS;

    // [buf][half][64x64] -- half hb holds keys 64*hb..64*hb+63 of the tile
    __shared__ __align__(16) unsigned short Klds[2][2][64 * 64];  // 32 KB
    __shared__ __align__(16) unsigned short Vlds[2][2][64 * 64];  // 32 KB

    const int t    = threadIdx.x;
    const int w    = t >> 6;
    const int lane = t & 63;
    const int l15  = lane & 15;
    const int quad = lane >> 4;

    const int koff0 = l15 * 64 + (quad ^ (l15 & 7)) * 8;
    const int koff1 = koff0 ^ 32;

    const int srow   = lane >> 3;
    const int schunk = (lane & 7) ^ srow;

    // Q B-frags: 4 m-tiles of 16 rows -> 64 q-rows per wave
    bf16x8 qf[4][2];
    #pragma unroll
    for (int m = 0; m < 4; ++m)
        #pragma unroll
        for (int kc = 0; kc < 2; ++kc)
            qf[m][kc] = *(const bf16x8*)
                &Q[(size_t)(q0 + 64 * w + 16 * m + l15) * HDIM + quad * 8 + 32 * kc];

    // O^T accumulators [te][m]: row=quad*4+r -> e, col=l15 -> qrow
    f32x4 OT[4][4];
    float lsum[4] = {0.f, 0.f, 0.f, 0.f};
    #pragma unroll
    for (int te = 0; te < 4; ++te)
        #pragma unroll
        for (int m = 0; m < 4; ++m) OT[te][m] = (f32x4){0.f, 0.f, 0.f, 0.f};

    // stage one 128-key K tile + matching V tile; 4 waves x 8 issues each
    auto stage = [&](int kt, int b) {
        #pragma unroll
        for (int hb = 0; hb < 2; ++hb) {
            #pragma unroll
            for (int i = 0; i < 2; ++i) {
                int rb = 16 * w + 8 * i;
                __builtin_amdgcn_global_load_lds(
                    (const GLOBAL_AS void*)&K[(size_t)(kbase + kt + 64 * hb + rb + srow) * HDIM
                                              + schunk * 8],
                    (LDS_AS void*)&Klds[b][hb][rb * 64], 16, 0, 0);
                __builtin_amdgcn_global_load_lds(
                    (const GLOBAL_AS void*)&Vt[(size_t)(rb + srow) * NPTS
                                               + kbase + kt + 64 * hb + schunk * 8],
                    (LDS_AS void*)&Vlds[b][hb][rb * 64], 16, 0, 0);
            }
        }
    };

    stage(0, 0);
    __syncthreads();
    int buf = 0;

    for (int kt = 0; kt < NPTS / 2; kt += 128) {
        // issue next stage first: a full body of latency cover before the
        // barrier's vmcnt(0) drain
        if (kt + 128 < NPTS / 2) stage(kt + 128, buf ^ 1);

        #pragma unroll
        for (int hb = 0; hb < 2; ++hb) {
            const unsigned short* Kl = Klds[buf][hb];
            const unsigned short* Vl = Vlds[buf][hb];

            bf16x8 pt[2][4];

            // Two 32-key sub-phases: kf/st transients live only within a
            // sub-phase (16+32 regs), folded straight into pt[kb].
            #pragma unroll
            for (int kb = 0; kb < 2; ++kb) {
                bf16x8 kf[2][2];
                #pragma unroll
                for (int kn = 0; kn < 2; ++kn) {
                    kf[kn][0] = *(const bf16x8*)&Kl[1024 * (2 * kb + kn) + koff0];
                    kf[kn][1] = *(const bf16x8*)&Kl[1024 * (2 * kb + kn) + koff1];
                }

                // S^T = K Q^T : st[kn][m], row=key(quad*4+r), col=qrow(l15)
                f32x4 st[2][4];
                #pragma unroll
                for (int kn = 0; kn < 2; ++kn)
                    #pragma unroll
                    for (int m = 0; m < 4; ++m) st[kn][m] = (f32x4){0.f, 0.f, 0.f, 0.f};
                #pragma unroll
                for (int kn = 0; kn < 2; ++kn)
                    #pragma unroll
                    for (int m = 0; m < 4; ++m) {
                        st[kn][m] = __builtin_amdgcn_mfma_f32_16x16x32_bf16(
                            kf[kn][0], qf[m][0], st[kn][m], 0, 0, 0);
                        st[kn][m] = __builtin_amdgcn_mfma_f32_16x16x32_bf16(
                            kf[kn][1], qf[m][1], st[kn][m], 0, 0, 0);
                    }

                // max-free softmax in registers: pt = bf16 exp2(S^T)
                #pragma unroll
                for (int m = 0; m < 4; ++m) {
                    float a0 = EXP2F(st[0][m][0]);
                    float a1 = EXP2F(st[0][m][1]);
                    float a2 = EXP2F(st[0][m][2]);
                    float a3 = EXP2F(st[0][m][3]);
                    float b0 = EXP2F(st[1][m][0]);
                    float b1 = EXP2F(st[1][m][1]);
                    float b2 = EXP2F(st[1][m][2]);
                    float b3 = EXP2F(st[1][m][3]);
                    lsum[m] += ((a0 + a1) + (a2 + a3)) + ((b0 + b1) + (b2 + b3));
                    union { uint4 u; bf16x8 v; } uu;
                    uu.u.x = pk2bf(a0, a1);
                    uu.u.y = pk2bf(a2, a3);
                    uu.u.z = pk2bf(b0, b1);
                    uu.u.w = pk2bf(b2, b3);
                    pt[kb][m] = uu.v;
                }
            }

            // V A-frags from LDS -- after softmax so st/kf are dead
            bf16x8 vf[4][2];
            #pragma unroll
            for (int te = 0; te < 4; ++te) {
                vf[te][0] = *(const bf16x8*)&Vl[1024 * te + koff0];
                vf[te][1] = *(const bf16x8*)&Vl[1024 * te + koff1];
            }

            // O^T += V^T P^T  (pure register path)
            #pragma unroll
            for (int te = 0; te < 4; ++te)
                #pragma unroll
                for (int m = 0; m < 4; ++m) {
                    OT[te][m] = __builtin_amdgcn_mfma_f32_16x16x32_bf16(
                        vf[te][0], pt[0][m], OT[te][m], 0, 0, 0);
                    OT[te][m] = __builtin_amdgcn_mfma_f32_16x16x32_bf16(
                        vf[te][1], pt[1][m], OT[te][m], 0, 0, 0);
                }
        }

        __syncthreads();   // Klds/Vlds[buf] reads done; next stage visible
        buf ^= 1;
    }

    // epilogue: l reduced across quads; write unnormalized O^T packed
    #pragma unroll
    for (int m = 0; m < 4; ++m) {
        float l = lsum[m];
        l += __shfl_xor(l, 16);
        l += __shfl_xor(l, 32);
        int n = q0 + 64 * w + 16 * m + l15;
        if (quad == 0) lp[n] = l;
        #pragma unroll
        for (int te = 0; te < 4; ++te) {
            uint2 pk;
            pk.x = pk2bf(OT[te][m][0], OT[te][m][1]);
            pk.y = pk2bf(OT[te][m][2], OT[te][m][3]);
            *(uint2*)&op[(size_t)n * DIM + h * HDIM + 16 * te + quad * 4] = pk;
        }
    }
}

// ---------------------------------------------------------------------------
// Merge k-split partials: op0 <- bf16((op0 + op1) / (l0 + l1))  in place.
// ---------------------------------------------------------------------------
__global__ __launch_bounds__(256) void reduce_kernel(
    unsigned short* __restrict__ op0, const unsigned short* __restrict__ op1,
    const float* __restrict__ l0, const float* __restrict__ l1)
{
    int gid = blockIdx.x * 256 + threadIdx.x;   // over N*DIM/4
    int n  = gid >> 7;
    int c4 = gid & 127;
    int h  = c4 >> 4;
    float inv = 1.0f / (l0[h * NPTS + n] + l1[h * NPTS + n]);
    ushort4 a = *(const ushort4*)&op0[(size_t)gid * 4];
    ushort4 b = *(const ushort4*)&op1[(size_t)gid * 4];
    uint2 o;
    o.x = pk2bf((bf2f(a.x) + bf2f(b.x)) * inv, (bf2f(a.y) + bf2f(b.y)) * inv);
    o.y = pk2bf((bf2f(a.z) + bf2f(b.z)) * inv, (bf2f(a.w) + bf2f(b.w)) * inv);
    *(uint2*)&op0[(size_t)gid * 4] = o;
}

// ---------------------------------------------------------------------------
// Output projection, bf16 MFMA, direct-global frags.
// ---------------------------------------------------------------------------
__global__ __launch_bounds__(256) void out_mfma_kernel(
    const unsigned short* __restrict__ cc,    // [N][512] bf16 normalized heads
    const unsigned short* __restrict__ wot,   // [512][512] bf16 [e_out][k]
    const float* __restrict__ bo, const float* __restrict__ x,
    float* __restrict__ outp)
{
    const int t = threadIdx.x, w = t >> 6, lane = t & 63;
    const int l15 = lane & 15, quad = lane >> 4;
    const int r0 = blockIdx.x * 128 + w * 32;
    const int c0 = blockIdx.y * 64;

    f32x4 O[2][4];
    #pragma unroll
    for (int mt = 0; mt < 2; ++mt)
        #pragma unroll
        for (int tn = 0; tn < 4; ++tn) O[mt][tn] = (f32x4){0.f, 0.f, 0.f, 0.f};

    for (int k0 = 0; k0 < DIM; k0 += 64) {
        bf16x8 af[2][2], bf[4][2];
        #pragma unroll
        for (int mt = 0; mt < 2; ++mt)
            #pragma unroll
            for (int kc = 0; kc < 2; ++kc)
                af[mt][kc] = *(const bf16x8*)
                    &cc[(size_t)(r0 + 16 * mt + l15) * DIM + k0 + quad * 8 + 32 * kc];
        #pragma unroll
        for (int tn = 0; tn < 4; ++tn)
            #pragma unroll
            for (int kc = 0; kc < 2; ++kc)
                bf[tn][kc] = *(const bf16x8*)
                    &wot[(size_t)(c0 + l15 + 16 * tn) * DIM + k0 + quad * 8 + 32 * kc];
        #pragma unroll
        for (int mt = 0; mt < 2; ++mt)
            #pragma unroll
            for (int tn = 0; tn < 4; ++tn) {
                O[mt][tn] = __builtin_amdgcn_mfma_f32_16x16x32_bf16(
                    af[mt][0], bf[tn][0], O[mt][tn], 0, 0, 0);
                O[mt][tn] = __builtin_amdgcn_mfma_f32_16x16x32_bf16(
                    af[mt][1], bf[tn][1], O[mt][tn], 0, 0, 0);
            }
    }

    #pragma unroll
    for (int mt = 0; mt < 2; ++mt)
        #pragma unroll
        for (int tn = 0; tn < 4; ++tn) {
            int e = c0 + l15 + 16 * tn;
            float be = bo[e];
            #pragma unroll
            for (int r = 0; r < 4; ++r) {
                int n = r0 + 16 * mt + quad * 4 + r;
                outp[(size_t)n * DIM + e] = O[mt][tn][r] + be + x[(size_t)n * DIM + e];
            }
        }
}

extern "C" void kernel_launch(void* const* d_in, const int* in_sizes, int n_in,
                              void* d_out, int out_size, void* d_ws, size_t ws_size,
                              hipStream_t stream) {
    const float* x  = (const float*)d_in[0];
    const float* Wq = (const float*)d_in[1];
    const float* bq = (const float*)d_in[2];
    const float* Wk = (const float*)d_in[3];
    const float* bk = (const float*)d_in[4];
    const float* Wv = (const float*)d_in[5];
    const float* bv = (const float*)d_in[6];
    const float* Wo = (const float*)d_in[7];
    const float* bo = (const float*)d_in[8];
    float* out = (float*)d_out;

    const size_t per = (size_t)NHEAD * NPTS * HDIM;            // 4M elems
    unsigned short* xbf   = (unsigned short*)d_ws;             //  8 MB
    unsigned short* wtq   = xbf + (size_t)NPTS * DIM;          //  1.5 MB
    unsigned short* wot   = wtq + (size_t)24 * HDIM * DIM;     //  0.5 MB
    unsigned short* q_bf  = wot + (size_t)DIM * DIM;           //  8 MB
    unsigned short* k_bf  = q_bf + per;                        //  8 MB
    unsigned short* vt_bf = k_bf + per;                        //  8 MB
    unsigned short* op0   = vt_bf + per;                       //  8 MB
    unsigned short* op1   = op0 + (size_t)NPTS * DIM;          //  8 MB
    float*          lpart = (float*)(op1 + (size_t)NPTS * DIM); // 512 KB
    // total ws: ~50.5 MB

    cvt_x_kernel<<<dim3(NPTS * DIM / 8 / 256), 256, 0, stream>>>(x, xbf);
    tr_w_kernel<<<dim3(8, 1, 24), 256, 0, stream>>>(Wq, Wk, Wv, wtq);
    tr_wo_kernel<<<dim3(8, 8), 256, 0, stream>>>(Wo, wot);
    qkv_mfma_kernel<<<dim3(NPTS / 128, 24), 256, 0, stream>>>(
        xbf, wtq, bq, bk, bv, q_bf, k_bf, vt_bf);
    attn_kernel<<<dim3(NPTS / 256, NHEAD, 2), 256, 0, stream>>>(
        q_bf, k_bf, vt_bf, op0, lpart);
    reduce_kernel<<<dim3(NPTS * DIM / 4 / 256), 256, 0, stream>>>(
        op0, op1, lpart, lpart + (size_t)NHEAD * NPTS);
    out_mfma_kernel<<<dim3(NPTS / 128, DIM / 64), 256, 0, stream>>>(
        op0, wot, bo, x, out);
}

// Round 6
// 355.178 us; speedup vs baseline: 1.0675x; 1.0675x over previous
//
#include <hip/hip_runtime.h>
#include <hip/hip_bf16.h>

#define NPTS 8192
#define DIM  512
#define NHEAD 8
#define HDIM 64

typedef short bf16x8 __attribute__((ext_vector_type(8)));   // 8 bf16 = 4 VGPRs
typedef float f32x4  __attribute__((ext_vector_type(4)));   // MFMA C/D

#define GLOBAL_AS __attribute__((address_space(1)))
#define LDS_AS    __attribute__((address_space(3)))

#if __has_builtin(__builtin_amdgcn_exp2f)
#define EXP2F(x) __builtin_amdgcn_exp2f(x)
#else
#define EXP2F(x) __expf((x) * 0.6931471805599453f)
#endif

// fp32 -> bf16 round-nearest-even (scalar)
__device__ __forceinline__ unsigned short f2bf(float f) {
    union { float f; unsigned int u; } v; v.f = f;
    unsigned int r = v.u + 0x7FFFu + ((v.u >> 16) & 1u);
    return (unsigned short)(r >> 16);
}
__device__ __forceinline__ float bf2f(unsigned short u) {
    union { unsigned int i; float f; } v; v.i = ((unsigned int)u) << 16;
    return v.f;
}
// packed 2x f32 -> bf16 pair (v_cvt_pk_bf16_f32 on gfx950)
__device__ __forceinline__ unsigned int pk2bf(float a, float b) {
    __hip_bfloat162 h = __float22bfloat162_rn(float2{a, b});
    union { __hip_bfloat162 h; unsigned int u; } v; v.h = h;
    return v.u;
}

// ---------------------------------------------------------------------------
// Prep 1: x fp32 -> bf16
// ---------------------------------------------------------------------------
__global__ __launch_bounds__(256) void cvt_x_kernel(
    const float* __restrict__ in, unsigned short* __restrict__ outp)
{
    int gid = blockIdx.x * 256 + threadIdx.x;   // over N*DIM/8
    float4 a = ((const float4*)in)[gid * 2];
    float4 b = ((const float4*)in)[gid * 2 + 1];
    uint4 u;
    u.x = pk2bf(a.x, a.y); u.y = pk2bf(a.z, a.w);
    u.z = pk2bf(b.x, b.y); u.w = pk2bf(b.z, b.w);
    ((uint4*)outp)[gid] = u;
}

// ---------------------------------------------------------------------------
// Prep 2: Wq/Wk/Wv [h][512][64] fp32 -> wtq [zh][64][512] bf16 (transposed)
// ---------------------------------------------------------------------------
__global__ __launch_bounds__(256) void tr_w_kernel(
    const float* __restrict__ Wq, const float* __restrict__ Wk,
    const float* __restrict__ Wv, unsigned short* __restrict__ wtq)
{
    int zh = blockIdx.z, z = zh >> 3, h = zh & 7;
    const float* src = (z == 0 ? Wq : z == 1 ? Wk : Wv) + (size_t)h * DIM * HDIM;
    unsigned short* dst = wtq + (size_t)zh * HDIM * DIM;
    int k0 = blockIdx.x * 64;
    __shared__ float tile[64][65];
    int t = threadIdx.x, c = t & 63, r = t >> 6;
    #pragma unroll
    for (int i = 0; i < 16; ++i)
        tile[r + 4 * i][c] = src[(size_t)(k0 + r + 4 * i) * HDIM + c];
    __syncthreads();
    #pragma unroll
    for (int i = 0; i < 16; ++i)
        dst[(size_t)(r + 4 * i) * DIM + k0 + c] = f2bf(tile[c][r + 4 * i]);
}

// ---------------------------------------------------------------------------
// Prep 3: Wo [512][512] fp32 -> wot [512][512] bf16 transposed ([e_out][k])
// ---------------------------------------------------------------------------
__global__ __launch_bounds__(256) void tr_wo_kernel(
    const float* __restrict__ Wo, unsigned short* __restrict__ wot)
{
    int k0 = blockIdx.x * 64, e0 = blockIdx.y * 64;
    __shared__ float tile[64][65];
    int t = threadIdx.x, c = t & 63, r = t >> 6;
    #pragma unroll
    for (int i = 0; i < 16; ++i)
        tile[r + 4 * i][c] = Wo[(size_t)(k0 + r + 4 * i) * DIM + e0 + c];
    __syncthreads();
    #pragma unroll
    for (int i = 0; i < 16; ++i)
        wot[(size_t)(e0 + r + 4 * i) * DIM + k0 + c] = f2bf(tile[c][r + 4 * i]);
}

// ---------------------------------------------------------------------------
// QKV projection, bf16 MFMA, direct-global frags.
//   z=0: q_bf[h][n][e]  (scale*log2e folded)   z=1: k_bf[h][n][e]
//   z=2: vtp[h][e][pi(n)] = V^T with the PV sigma-permutation pre-applied
//        within each 32-key block (pos = 8*quad + 4*mt + r holds
//        key = 16*mt + 4*quad + r) -- matches P^T's B-frag key order.
// ---------------------------------------------------------------------------
__global__ __launch_bounds__(256) void qkv_mfma_kernel(
    const unsigned short* __restrict__ xbf,   // [N][512] bf16
    const unsigned short* __restrict__ wtq,   // [24][64][512] bf16
    const float* __restrict__ bq, const float* __restrict__ bk,
    const float* __restrict__ bv,
    unsigned short* __restrict__ q_bf, unsigned short* __restrict__ k_bf,
    unsigned short* __restrict__ vt_bf)
{
    const int zh = blockIdx.y, z = zh >> 3, h = zh & 7;
    const unsigned short* W = wtq + (size_t)zh * HDIM * DIM;
    const float* b = (z == 0 ? bq : z == 1 ? bk : bv) + h * HDIM;
    const int t = threadIdx.x, w = t >> 6, lane = t & 63;
    const int l15 = lane & 15, quad = lane >> 4;
    const int r0 = blockIdx.x * 128 + w * 32;

    f32x4 O[2][4];
    #pragma unroll
    for (int mt = 0; mt < 2; ++mt)
        #pragma unroll
        for (int tn = 0; tn < 4; ++tn) O[mt][tn] = (f32x4){0.f, 0.f, 0.f, 0.f};

    for (int k0 = 0; k0 < DIM; k0 += 64) {
        bf16x8 af[2][2], bf[4][2];
        #pragma unroll
        for (int mt = 0; mt < 2; ++mt)
            #pragma unroll
            for (int kc = 0; kc < 2; ++kc)
                af[mt][kc] = *(const bf16x8*)
                    &xbf[(size_t)(r0 + 16 * mt + l15) * DIM + k0 + quad * 8 + 32 * kc];
        #pragma unroll
        for (int tn = 0; tn < 4; ++tn)
            #pragma unroll
            for (int kc = 0; kc < 2; ++kc)
                bf[tn][kc] = *(const bf16x8*)
                    &W[(size_t)(l15 + 16 * tn) * DIM + k0 + quad * 8 + 32 * kc];
        #pragma unroll
        for (int mt = 0; mt < 2; ++mt)
            #pragma unroll
            for (int tn = 0; tn < 4; ++tn) {
                O[mt][tn] = __builtin_amdgcn_mfma_f32_16x16x32_bf16(
                    af[mt][0], bf[tn][0], O[mt][tn], 0, 0, 0);
                O[mt][tn] = __builtin_amdgcn_mfma_f32_16x16x32_bf16(
                    af[mt][1], bf[tn][1], O[mt][tn], 0, 0, 0);
            }
    }

    if (z < 2) {
        unsigned short* outp = (z == 0 ? q_bf : k_bf) + (size_t)h * NPTS * HDIM;
        const float sc = (z == 0) ? 0.18033688011112042f : 1.0f;  // 0.125*log2e | 1
        #pragma unroll
        for (int mt = 0; mt < 2; ++mt)
            #pragma unroll
            for (int tn = 0; tn < 4; ++tn) {
                int e = l15 + 16 * tn;
                float be = b[e];
                #pragma unroll
                for (int r = 0; r < 4; ++r) {
                    int n = r0 + 16 * mt + quad * 4 + r;
                    outp[(size_t)n * HDIM + e] = f2bf((O[mt][tn][r] + be) * sc);
                }
            }
    } else {
        unsigned short* vt = vt_bf + (size_t)h * HDIM * NPTS;
        #pragma unroll
        for (int mt = 0; mt < 2; ++mt)
            #pragma unroll
            for (int tn = 0; tn < 4; ++tn) {
                int e = l15 + 16 * tn;
                float be = b[e];
                uint2 pk;
                pk.x = pk2bf(O[mt][tn][0] + be, O[mt][tn][1] + be);
                pk.y = pk2bf(O[mt][tn][2] + be, O[mt][tn][3] + be);
                // sigma-permuted position within this 32-row block
                *(uint2*)&vt[(size_t)e * NPTS + r0 + quad * 8 + mt * 4] = pk;
            }
    }
}

// ---------------------------------------------------------------------------
// MFMA flash attention, R12b (third submit of the R12 algorithm; rounds 4-5
// were container failures with no kernel signal; this version inlines the
// staging lambda and brace-inits the ones frag -- semantics identical):
// exact R9 structure (proven 191.7us) minus inner-loop VALU:
//   (a) softmax row-sum in the matrix pipe: Lacc[m] += ones x pt[kb][m]
//       (all-ones A-frag -> permutation-invariant; replaces 32 v_add/iter
//       and the epilogue shfl pair).
//   (b) staging addresses hoisted: running global pointers bumped by
//       constant strides per tile.
// Everything else identical to R9: 32 q-rows/wave, 64-key double-buffered
// K+V tiles (32 KB LDS), XOR chunk swizzle, V-frags after softmax, k-split 2.
// ---------------------------------------------------------------------------
__global__ __launch_bounds__(256) void attn_kernel(
    const unsigned short* __restrict__ qg,   // [H][N][64] bf16, pre-scaled
    const unsigned short* __restrict__ kg,   // [H][N][64] bf16
    const unsigned short* __restrict__ vtg,  // [H][64][N] bf16, sigma-permuted
    unsigned short* __restrict__ opart,      // [2][N][DIM] bf16 unnormalized
    float* __restrict__ lpart)               // [2][H][N] fp32
{
    const int h  = blockIdx.y;
    const int ks = blockIdx.z;
    const int q0 = blockIdx.x * 128;
    const int kbase = ks * (NPTS / 2);
    const unsigned short* Q  = qg  + (size_t)h * NPTS * HDIM;
    const unsigned short* K  = kg  + (size_t)h * NPTS * HDIM;
    const unsigned short* Vt = vtg + (size_t)h * HDIM * NPTS;
    unsigned short* op = opart + (size_t)ks * NPTS * DIM;
    float* lp = lpart + (size_t)(ks * NHEAD + h) * NPTS;

    __shared__ __align__(16) unsigned short Klds[2][64 * 64];  // 16 KB
    __shared__ __align__(16) unsigned short Vlds[2][64 * 64];  // 16 KB

    const int t    = threadIdx.x;
    const int w    = t >> 6;
    const int lane = t & 63;
    const int l15  = lane & 15;
    const int quad = lane >> 4;

    const int koff0 = l15 * 64 + (quad ^ (l15 & 7)) * 8;
    const int koff1 = koff0 ^ 32;

    const int srow   = lane >> 3;
    const int schunk = (lane & 7) ^ srow;

    // Q B-frags
    bf16x8 qf[2][2];
    #pragma unroll
    for (int m = 0; m < 2; ++m)
        #pragma unroll
        for (int kc = 0; kc < 2; ++kc)
            qf[m][kc] = *(const bf16x8*)
                &Q[(size_t)(q0 + 32 * w + 16 * m + l15) * HDIM + quad * 8 + 32 * kc];

    // all-ones bf16 A-frag for the row-sum MFMA (0x3F80 == bf16 1.0)
    const bf16x8 ones = {(short)0x3F80, (short)0x3F80, (short)0x3F80,
                         (short)0x3F80, (short)0x3F80, (short)0x3F80,
                         (short)0x3F80, (short)0x3F80};

    // O^T accumulators [te][m]: row=quad*4+r -> e, col=l15 -> qrow
    f32x4 OT[4][2];
    f32x4 Lacc[2];
    #pragma unroll
    for (int te = 0; te < 4; ++te)
        #pragma unroll
        for (int m = 0; m < 2; ++m) OT[te][m] = (f32x4){0.f, 0.f, 0.f, 0.f};
    #pragma unroll
    for (int m = 0; m < 2; ++m) Lacc[m] = (f32x4){0.f, 0.f, 0.f, 0.f};

    // running staging pointers (advanced by constant strides per tile)
    const unsigned short* Ks  = K  + (size_t)(kbase + 16 * w + srow) * HDIM
                                   + schunk * 8;
    const unsigned short* Vs0 = Vt + (size_t)(16 * w + srow) * NPTS
                                   + kbase + schunk * 8;
    const unsigned short* Vs1 = Vs0 + (size_t)8 * NPTS;

    // prologue: stage tile 0 into buffer 0 (4 waves x 4 issues)
    __builtin_amdgcn_global_load_lds((const GLOBAL_AS void*)Ks,
        (LDS_AS void*)&Klds[0][(16 * w) * 64], 16, 0, 0);
    __builtin_amdgcn_global_load_lds((const GLOBAL_AS void*)(Ks + 8 * HDIM),
        (LDS_AS void*)&Klds[0][(16 * w + 8) * 64], 16, 0, 0);
    __builtin_amdgcn_global_load_lds((const GLOBAL_AS void*)Vs0,
        (LDS_AS void*)&Vlds[0][(16 * w) * 64], 16, 0, 0);
    __builtin_amdgcn_global_load_lds((const GLOBAL_AS void*)Vs1,
        (LDS_AS void*)&Vlds[0][(16 * w + 8) * 64], 16, 0, 0);
    Ks += 64 * HDIM; Vs0 += 64; Vs1 += 64;
    __syncthreads();
    int buf = 0;

    for (int kt = 0; kt < NPTS / 2; kt += 64) {
        // issue next stage first: a full body of latency cover before the
        // barrier's vmcnt(0) drain
        if (kt + 64 < NPTS / 2) {
            int nb = buf ^ 1;
            __builtin_amdgcn_global_load_lds((const GLOBAL_AS void*)Ks,
                (LDS_AS void*)&Klds[nb][(16 * w) * 64], 16, 0, 0);
            __builtin_amdgcn_global_load_lds((const GLOBAL_AS void*)(Ks + 8 * HDIM),
                (LDS_AS void*)&Klds[nb][(16 * w + 8) * 64], 16, 0, 0);
            __builtin_amdgcn_global_load_lds((const GLOBAL_AS void*)Vs0,
                (LDS_AS void*)&Vlds[nb][(16 * w) * 64], 16, 0, 0);
            __builtin_amdgcn_global_load_lds((const GLOBAL_AS void*)Vs1,
                (LDS_AS void*)&Vlds[nb][(16 * w + 8) * 64], 16, 0, 0);
            Ks += 64 * HDIM; Vs0 += 64; Vs1 += 64;
        }

        // K A-frags from LDS
        bf16x8 kf[4][2];
        #pragma unroll
        for (int kn = 0; kn < 4; ++kn) {
            kf[kn][0] = *(const bf16x8*)&Klds[buf][1024 * kn + koff0];
            kf[kn][1] = *(const bf16x8*)&Klds[buf][1024 * kn + koff1];
        }

        // S^T = K Q^T : st[kn][m], row=key(quad*4+r), col=qrow(l15)
        f32x4 st[4][2];
        #pragma unroll
        for (int kn = 0; kn < 4; ++kn)
            #pragma unroll
            for (int m = 0; m < 2; ++m) st[kn][m] = (f32x4){0.f, 0.f, 0.f, 0.f};
        #pragma unroll
        for (int kn = 0; kn < 4; ++kn)
            #pragma unroll
            for (int m = 0; m < 2; ++m) {
                st[kn][m] = __builtin_amdgcn_mfma_f32_16x16x32_bf16(
                    kf[kn][0], qf[m][0], st[kn][m], 0, 0, 0);
                st[kn][m] = __builtin_amdgcn_mfma_f32_16x16x32_bf16(
                    kf[kn][1], qf[m][1], st[kn][m], 0, 0, 0);
            }

        // max-free softmax in registers: pt = bf16 exp2(S^T), packed cvt
        bf16x8 pt[2][2];
        #pragma unroll
        for (int kb = 0; kb < 2; ++kb)
            #pragma unroll
            for (int m = 0; m < 2; ++m) {
                float a0 = EXP2F(st[2 * kb + 0][m][0]);
                float a1 = EXP2F(st[2 * kb + 0][m][1]);
                float a2 = EXP2F(st[2 * kb + 0][m][2]);
                float a3 = EXP2F(st[2 * kb + 0][m][3]);
                float b0 = EXP2F(st[2 * kb + 1][m][0]);
                float b1 = EXP2F(st[2 * kb + 1][m][1]);
                float b2 = EXP2F(st[2 * kb + 1][m][2]);
                float b3 = EXP2F(st[2 * kb + 1][m][3]);
                union { uint4 u; bf16x8 v; } uu;
                uu.u.x = pk2bf(a0, a1);
                uu.u.y = pk2bf(a2, a3);
                uu.u.z = pk2bf(b0, b1);
                uu.u.w = pk2bf(b2, b3);
                pt[kb][m] = uu.v;
            }

        // V A-frags from LDS (identical pattern to kf; kf regs dead by now)
        bf16x8 vf[4][2];
        #pragma unroll
        for (int te = 0; te < 4; ++te) {
            vf[te][0] = *(const bf16x8*)&Vlds[buf][1024 * te + koff0];
            vf[te][1] = *(const bf16x8*)&Vlds[buf][1024 * te + koff1];
        }

        // row-sum in the matrix pipe: Lacc[m] += ones x pt (all rows equal l)
        #pragma unroll
        for (int kb = 0; kb < 2; ++kb)
            #pragma unroll
            for (int m = 0; m < 2; ++m)
                Lacc[m] = __builtin_amdgcn_mfma_f32_16x16x32_bf16(
                    ones, pt[kb][m], Lacc[m], 0, 0, 0);

        // O^T += V^T P^T  (pure register path)
        #pragma unroll
        for (int te = 0; te < 4; ++te)
            #pragma unroll
            for (int m = 0; m < 2; ++m) {
                OT[te][m] = __builtin_amdgcn_mfma_f32_16x16x32_bf16(
                    vf[te][0], pt[0][m], OT[te][m], 0, 0, 0);
                OT[te][m] = __builtin_amdgcn_mfma_f32_16x16x32_bf16(
                    vf[te][1], pt[1][m], OT[te][m], 0, 0, 0);
            }

        __syncthreads();   // Klds/Vlds[buf] reads done; next stage visible
        buf ^= 1;
    }

    // epilogue: l comes straight out of Lacc (all components/quads equal);
    // write unnormalized O^T packed
    #pragma unroll
    for (int m = 0; m < 2; ++m) {
        int n = q0 + 32 * w + 16 * m + l15;
        if (quad == 0) lp[n] = Lacc[m][0];
        #pragma unroll
        for (int te = 0; te < 4; ++te) {
            uint2 pk;
            pk.x = pk2bf(OT[te][m][0], OT[te][m][1]);
            pk.y = pk2bf(OT[te][m][2], OT[te][m][3]);
            *(uint2*)&op[(size_t)n * DIM + h * HDIM + 16 * te + quad * 4] = pk;
        }
    }
}

// ---------------------------------------------------------------------------
// Merge k-split partials: op0 <- bf16((op0 + op1) / (l0 + l1))  in place.
// ---------------------------------------------------------------------------
__global__ __launch_bounds__(256) void reduce_kernel(
    unsigned short* __restrict__ op0, const unsigned short* __restrict__ op1,
    const float* __restrict__ l0, const float* __restrict__ l1)
{
    int gid = blockIdx.x * 256 + threadIdx.x;   // over N*DIM/4
    int n  = gid >> 7;
    int c4 = gid & 127;
    int h  = c4 >> 4;
    float inv = 1.0f / (l0[h * NPTS + n] + l1[h * NPTS + n]);
    ushort4 a = *(const ushort4*)&op0[(size_t)gid * 4];
    ushort4 b = *(const ushort4*)&op1[(size_t)gid * 4];
    uint2 o;
    o.x = pk2bf((bf2f(a.x) + bf2f(b.x)) * inv, (bf2f(a.y) + bf2f(b.y)) * inv);
    o.y = pk2bf((bf2f(a.z) + bf2f(b.z)) * inv, (bf2f(a.w) + bf2f(b.w)) * inv);
    *(uint2*)&op0[(size_t)gid * 4] = o;
}

// ---------------------------------------------------------------------------
// Output projection, bf16 MFMA, direct-global frags.
// ---------------------------------------------------------------------------
__global__ __launch_bounds__(256) void out_mfma_kernel(
    const unsigned short* __restrict__ cc,    // [N][512] bf16 normalized heads
    const unsigned short* __restrict__ wot,   // [512][512] bf16 [e_out][k]
    const float* __restrict__ bo, const float* __restrict__ x,
    float* __restrict__ outp)
{
    const int t = threadIdx.x, w = t >> 6, lane = t & 63;
    const int l15 = lane & 15, quad = lane >> 4;
    const int r0 = blockIdx.x * 128 + w * 32;
    const int c0 = blockIdx.y * 64;

    f32x4 O[2][4];
    #pragma unroll
    for (int mt = 0; mt < 2; ++mt)
        #pragma unroll
        for (int tn = 0; tn < 4; ++tn) O[mt][tn] = (f32x4){0.f, 0.f, 0.f, 0.f};

    for (int k0 = 0; k0 < DIM; k0 += 64) {
        bf16x8 af[2][2], bf[4][2];
        #pragma unroll
        for (int mt = 0; mt < 2; ++mt)
            #pragma unroll
            for (int kc = 0; kc < 2; ++kc)
                af[mt][kc] = *(const bf16x8*)
                    &cc[(size_t)(r0 + 16 * mt + l15) * DIM + k0 + quad * 8 + 32 * kc];
        #pragma unroll
        for (int tn = 0; tn < 4; ++tn)
            #pragma unroll
            for (int kc = 0; kc < 2; ++kc)
                bf[tn][kc] = *(const bf16x8*)
                    &wot[(size_t)(c0 + l15 + 16 * tn) * DIM + k0 + quad * 8 + 32 * kc];
        #pragma unroll
        for (int mt = 0; mt < 2; ++mt)
            #pragma unroll
            for (int tn = 0; tn < 4; ++tn) {
                O[mt][tn] = __builtin_amdgcn_mfma_f32_16x16x32_bf16(
                    af[mt][0], bf[tn][0], O[mt][tn], 0, 0, 0);
                O[mt][tn] = __builtin_amdgcn_mfma_f32_16x16x32_bf16(
                    af[mt][1], bf[tn][1], O[mt][tn], 0, 0, 0);
            }
    }

    #pragma unroll
    for (int mt = 0; mt < 2; ++mt)
        #pragma unroll
        for (int tn = 0; tn < 4; ++tn) {
            int e = c0 + l15 + 16 * tn;
            float be = bo[e];
            #pragma unroll
            for (int r = 0; r < 4; ++r) {
                int n = r0 + 16 * mt + quad * 4 + r;
                outp[(size_t)n * DIM + e] = O[mt][tn][r] + be + x[(size_t)n * DIM + e];
            }
        }
}

extern "C" void kernel_launch(void* const* d_in, const int* in_sizes, int n_in,
                              void* d_out, int out_size, void* d_ws, size_t ws_size,
                              hipStream_t stream) {
    const float* x  = (const float*)d_in[0];
    const float* Wq = (const float*)d_in[1];
    const float* bq = (const float*)d_in[2];
    const float* Wk = (const float*)d_in[3];
    const float* bk = (const float*)d_in[4];
    const float* Wv = (const float*)d_in[5];
    const float* bv = (const float*)d_in[6];
    const float* Wo = (const float*)d_in[7];
    const float* bo = (const float*)d_in[8];
    float* out = (float*)d_out;

    const size_t per = (size_t)NHEAD * NPTS * HDIM;            // 4M elems
    unsigned short* xbf   = (unsigned short*)d_ws;             //  8 MB
    unsigned short* wtq   = xbf + (size_t)NPTS * DIM;          //  1.5 MB
    unsigned short* wot   = wtq + (size_t)24 * HDIM * DIM;     //  0.5 MB
    unsigned short* q_bf  = wot + (size_t)DIM * DIM;           //  8 MB
    unsigned short* k_bf  = q_bf + per;                        //  8 MB
    unsigned short* vt_bf = k_bf + per;                        //  8 MB
    unsigned short* op0   = vt_bf + per;                       //  8 MB
    unsigned short* op1   = op0 + (size_t)NPTS * DIM;          //  8 MB
    float*          lpart = (float*)(op1 + (size_t)NPTS * DIM); // 512 KB
    // total ws: ~50.5 MB

    cvt_x_kernel<<<dim3(NPTS * DIM / 8 / 256), 256, 0, stream>>>(x, xbf);
    tr_w_kernel<<<dim3(8, 1, 24), 256, 0, stream>>>(Wq, Wk, Wv, wtq);
    tr_wo_kernel<<<dim3(8, 8), 256, 0, stream>>>(Wo, wot);
    qkv_mfma_kernel<<<dim3(NPTS / 128, 24), 256, 0, stream>>>(
        xbf, wtq, bq, bk, bv, q_bf, k_bf, vt_bf);
    attn_kernel<<<dim3(NPTS / 128, NHEAD, 2), 256, 0, stream>>>(
        q_bf, k_bf, vt_bf, op0, lpart);
    reduce_kernel<<<dim3(NPTS * DIM / 4 / 256), 256, 0, stream>>>(
        op0, op1, lpart, lpart + (size_t)NHEAD * NPTS);
    out_mfma_kernel<<<dim3(NPTS / 128, DIM / 64), 256, 0, stream>>>(
        op0, wot, bo, x, out);
}

// Round 7
// 350.732 us; speedup vs baseline: 1.0811x; 1.0127x over previous
//
#include <hip/hip_runtime.h>
#include <hip/hip_bf16.h>

#define NPTS 8192
#define DIM  512
#define NHEAD 8
#define HDIM 64

typedef short bf16x8 __attribute__((ext_vector_type(8)));   // 8 bf16 = 4 VGPRs
typedef float f32x4  __attribute__((ext_vector_type(4)));   // MFMA C/D

#define GLOBAL_AS __attribute__((address_space(1)))
#define LDS_AS    __attribute__((address_space(3)))

#if __has_builtin(__builtin_amdgcn_exp2f)
#define EXP2F(x) __builtin_amdgcn_exp2f(x)
#else
#define EXP2F(x) __expf((x) * 0.6931471805599453f)
#endif

// fp32 -> bf16 round-nearest-even (scalar)
__device__ __forceinline__ unsigned short f2bf(float f) {
    union { float f; unsigned int u; } v; v.f = f;
    unsigned int r = v.u + 0x7FFFu + ((v.u >> 16) & 1u);
    return (unsigned short)(r >> 16);
}
__device__ __forceinline__ float bf2f(unsigned short u) {
    union { unsigned int i; float f; } v; v.i = ((unsigned int)u) << 16;
    return v.f;
}
// packed 2x f32 -> bf16 pair (v_cvt_pk_bf16_f32 on gfx950)
__device__ __forceinline__ unsigned int pk2bf(float a, float b) {
    __hip_bfloat162 h = __float22bfloat162_rn(float2{a, b});
    union { __hip_bfloat162 h; unsigned int u; } v; v.h = h;
    return v.u;
}

// ---------------------------------------------------------------------------
// Prep 1: x fp32 -> bf16
// ---------------------------------------------------------------------------
__global__ __launch_bounds__(256) void cvt_x_kernel(
    const float* __restrict__ in, unsigned short* __restrict__ outp)
{
    int gid = blockIdx.x * 256 + threadIdx.x;   // over N*DIM/8
    float4 a = ((const float4*)in)[gid * 2];
    float4 b = ((const float4*)in)[gid * 2 + 1];
    uint4 u;
    u.x = pk2bf(a.x, a.y); u.y = pk2bf(a.z, a.w);
    u.z = pk2bf(b.x, b.y); u.w = pk2bf(b.z, b.w);
    ((uint4*)outp)[gid] = u;
}

// ---------------------------------------------------------------------------
// Prep 2: Wq/Wk/Wv [h][512][64] fp32 -> wtq [zh][64][512] bf16 (transposed)
// ---------------------------------------------------------------------------
__global__ __launch_bounds__(256) void tr_w_kernel(
    const float* __restrict__ Wq, const float* __restrict__ Wk,
    const float* __restrict__ Wv, unsigned short* __restrict__ wtq)
{
    int zh = blockIdx.z, z = zh >> 3, h = zh & 7;
    const float* src = (z == 0 ? Wq : z == 1 ? Wk : Wv) + (size_t)h * DIM * HDIM;
    unsigned short* dst = wtq + (size_t)zh * HDIM * DIM;
    int k0 = blockIdx.x * 64;
    __shared__ float tile[64][65];
    int t = threadIdx.x, c = t & 63, r = t >> 6;
    #pragma unroll
    for (int i = 0; i < 16; ++i)
        tile[r + 4 * i][c] = src[(size_t)(k0 + r + 4 * i) * HDIM + c];
    __syncthreads();
    #pragma unroll
    for (int i = 0; i < 16; ++i)
        dst[(size_t)(r + 4 * i) * DIM + k0 + c] = f2bf(tile[c][r + 4 * i]);
}

// ---------------------------------------------------------------------------
// Prep 3: Wo [512][512] fp32 -> wot [512][512] bf16 transposed ([e_out][k])
// ---------------------------------------------------------------------------
__global__ __launch_bounds__(256) void tr_wo_kernel(
    const float* __restrict__ Wo, unsigned short* __restrict__ wot)
{
    int k0 = blockIdx.x * 64, e0 = blockIdx.y * 64;
    __shared__ float tile[64][65];
    int t = threadIdx.x, c = t & 63, r = t >> 6;
    #pragma unroll
    for (int i = 0; i < 16; ++i)
        tile[r + 4 * i][c] = Wo[(size_t)(k0 + r + 4 * i) * DIM + e0 + c];
    __syncthreads();
    #pragma unroll
    for (int i = 0; i < 16; ++i)
        wot[(size_t)(e0 + r + 4 * i) * DIM + k0 + c] = f2bf(tile[c][r + 4 * i]);
}

// ---------------------------------------------------------------------------
// QKV projection, bf16 MFMA, direct-global frags.
//   z=0: q_bf[h][n][e]  (scale*log2e folded)   z=1: k_bf[h][n][e]
//   z=2: vtp[h][e][pi(n)] = V^T with the PV sigma-permutation pre-applied
//        within each 32-key block (pos = 8*quad + 4*mt + r holds
//        key = 16*mt + 4*quad + r) -- matches P^T's B-frag key order.
// ---------------------------------------------------------------------------
__global__ __launch_bounds__(256) void qkv_mfma_kernel(
    const unsigned short* __restrict__ xbf,   // [N][512] bf16
    const unsigned short* __restrict__ wtq,   // [24][64][512] bf16
    const float* __restrict__ bq, const float* __restrict__ bk,
    const float* __restrict__ bv,
    unsigned short* __restrict__ q_bf, unsigned short* __restrict__ k_bf,
    unsigned short* __restrict__ vt_bf)
{
    const int zh = blockIdx.y, z = zh >> 3, h = zh & 7;
    const unsigned short* W = wtq + (size_t)zh * HDIM * DIM;
    const float* b = (z == 0 ? bq : z == 1 ? bk : bv) + h * HDIM;
    const int t = threadIdx.x, w = t >> 6, lane = t & 63;
    const int l15 = lane & 15, quad = lane >> 4;
    const int r0 = blockIdx.x * 128 + w * 32;

    f32x4 O[2][4];
    #pragma unroll
    for (int mt = 0; mt < 2; ++mt)
        #pragma unroll
        for (int tn = 0; tn < 4; ++tn) O[mt][tn] = (f32x4){0.f, 0.f, 0.f, 0.f};

    for (int k0 = 0; k0 < DIM; k0 += 64) {
        bf16x8 af[2][2], bf[4][2];
        #pragma unroll
        for (int mt = 0; mt < 2; ++mt)
            #pragma unroll
            for (int kc = 0; kc < 2; ++kc)
                af[mt][kc] = *(const bf16x8*)
                    &xbf[(size_t)(r0 + 16 * mt + l15) * DIM + k0 + quad * 8 + 32 * kc];
        #pragma unroll
        for (int tn = 0; tn < 4; ++tn)
            #pragma unroll
            for (int kc = 0; kc < 2; ++kc)
                bf[tn][kc] = *(const bf16x8*)
                    &W[(size_t)(l15 + 16 * tn) * DIM + k0 + quad * 8 + 32 * kc];
        #pragma unroll
        for (int mt = 0; mt < 2; ++mt)
            #pragma unroll
            for (int tn = 0; tn < 4; ++tn) {
                O[mt][tn] = __builtin_amdgcn_mfma_f32_16x16x32_bf16(
                    af[mt][0], bf[tn][0], O[mt][tn], 0, 0, 0);
                O[mt][tn] = __builtin_amdgcn_mfma_f32_16x16x32_bf16(
                    af[mt][1], bf[tn][1], O[mt][tn], 0, 0, 0);
            }
    }

    if (z < 2) {
        unsigned short* outp = (z == 0 ? q_bf : k_bf) + (size_t)h * NPTS * HDIM;
        const float sc = (z == 0) ? 0.18033688011112042f : 1.0f;  // 0.125*log2e | 1
        #pragma unroll
        for (int mt = 0; mt < 2; ++mt)
            #pragma unroll
            for (int tn = 0; tn < 4; ++tn) {
                int e = l15 + 16 * tn;
                float be = b[e];
                #pragma unroll
                for (int r = 0; r < 4; ++r) {
                    int n = r0 + 16 * mt + quad * 4 + r;
                    outp[(size_t)n * HDIM + e] = f2bf((O[mt][tn][r] + be) * sc);
                }
            }
    } else {
        unsigned short* vt = vt_bf + (size_t)h * HDIM * NPTS;
        #pragma unroll
        for (int mt = 0; mt < 2; ++mt)
            #pragma unroll
            for (int tn = 0; tn < 4; ++tn) {
                int e = l15 + 16 * tn;
                float be = b[e];
                uint2 pk;
                pk.x = pk2bf(O[mt][tn][0] + be, O[mt][tn][1] + be);
                pk.y = pk2bf(O[mt][tn][2] + be, O[mt][tn][3] + be);
                // sigma-permuted position within this 32-row block
                *(uint2*)&vt[(size_t)e * NPTS + r0 + quad * 8 + mt * 4] = pk;
            }
    }
}

// ---------------------------------------------------------------------------
// MFMA flash attention, R13: R12b structure with phase-overlap reorder.
// R12b post-mortem: attn time is EXACTLY additive in {LDS-read cyc + MFMA cyc
// + VALU cyc} (7200 cyc/iter measured vs ~7100 summed) -- the per-iteration
// barrier phase-locks all 16 waves/CU into lockstep bursts: kf-read burst
// (MFMA idle), QK burst (LDS idle), softmax, vf-read burst, PV. Zero
// cross-pipe overlap. Fix: split the V-frag reads -- issue te=0,1 right
// after the kf reads (their LDS traffic drains under the QK MFMA burst) and
// te=2,3 after softmax (drains under Lacc + PV-te01 MFMAs). Independent of
// QK, so semantics unchanged. VGPR peak ~115 (only half of vf early),
// staying under the 128 occupancy step (R11's cliff).
// ---------------------------------------------------------------------------
__global__ __launch_bounds__(256) void attn_kernel(
    const unsigned short* __restrict__ qg,   // [H][N][64] bf16, pre-scaled
    const unsigned short* __restrict__ kg,   // [H][N][64] bf16
    const unsigned short* __restrict__ vtg,  // [H][64][N] bf16, sigma-permuted
    unsigned short* __restrict__ opart,      // [2][N][DIM] bf16 unnormalized
    float* __restrict__ lpart)               // [2][H][N] fp32
{
    const int h  = blockIdx.y;
    const int ks = blockIdx.z;
    const int q0 = blockIdx.x * 128;
    const int kbase = ks * (NPTS / 2);
    const unsigned short* Q  = qg  + (size_t)h * NPTS * HDIM;
    const unsigned short* K  = kg  + (size_t)h * NPTS * HDIM;
    const unsigned short* Vt = vtg + (size_t)h * HDIM * NPTS;
    unsigned short* op = opart + (size_t)ks * NPTS * DIM;
    float* lp = lpart + (size_t)(ks * NHEAD + h) * NPTS;

    __shared__ __align__(16) unsigned short Klds[2][64 * 64];  // 16 KB
    __shared__ __align__(16) unsigned short Vlds[2][64 * 64];  // 16 KB

    const int t    = threadIdx.x;
    const int w    = t >> 6;
    const int lane = t & 63;
    const int l15  = lane & 15;
    const int quad = lane >> 4;

    const int koff0 = l15 * 64 + (quad ^ (l15 & 7)) * 8;
    const int koff1 = koff0 ^ 32;

    const int srow   = lane >> 3;
    const int schunk = (lane & 7) ^ srow;

    // Q B-frags
    bf16x8 qf[2][2];
    #pragma unroll
    for (int m = 0; m < 2; ++m)
        #pragma unroll
        for (int kc = 0; kc < 2; ++kc)
            qf[m][kc] = *(const bf16x8*)
                &Q[(size_t)(q0 + 32 * w + 16 * m + l15) * HDIM + quad * 8 + 32 * kc];

    // all-ones bf16 A-frag for the row-sum MFMA (0x3F80 == bf16 1.0)
    const bf16x8 ones = {(short)0x3F80, (short)0x3F80, (short)0x3F80,
                         (short)0x3F80, (short)0x3F80, (short)0x3F80,
                         (short)0x3F80, (short)0x3F80};

    // O^T accumulators [te][m]: row=quad*4+r -> e, col=l15 -> qrow
    f32x4 OT[4][2];
    f32x4 Lacc[2];
    #pragma unroll
    for (int te = 0; te < 4; ++te)
        #pragma unroll
        for (int m = 0; m < 2; ++m) OT[te][m] = (f32x4){0.f, 0.f, 0.f, 0.f};
    #pragma unroll
    for (int m = 0; m < 2; ++m) Lacc[m] = (f32x4){0.f, 0.f, 0.f, 0.f};

    // running staging pointers (advanced by constant strides per tile)
    const unsigned short* Ks  = K  + (size_t)(kbase + 16 * w + srow) * HDIM
                                   + schunk * 8;
    const unsigned short* Vs0 = Vt + (size_t)(16 * w + srow) * NPTS
                                   + kbase + schunk * 8;
    const unsigned short* Vs1 = Vs0 + (size_t)8 * NPTS;

    // prologue: stage tile 0 into buffer 0 (4 waves x 4 issues)
    __builtin_amdgcn_global_load_lds((const GLOBAL_AS void*)Ks,
        (LDS_AS void*)&Klds[0][(16 * w) * 64], 16, 0, 0);
    __builtin_amdgcn_global_load_lds((const GLOBAL_AS void*)(Ks + 8 * HDIM),
        (LDS_AS void*)&Klds[0][(16 * w + 8) * 64], 16, 0, 0);
    __builtin_amdgcn_global_load_lds((const GLOBAL_AS void*)Vs0,
        (LDS_AS void*)&Vlds[0][(16 * w) * 64], 16, 0, 0);
    __builtin_amdgcn_global_load_lds((const GLOBAL_AS void*)Vs1,
        (LDS_AS void*)&Vlds[0][(16 * w + 8) * 64], 16, 0, 0);
    Ks += 64 * HDIM; Vs0 += 64; Vs1 += 64;
    __syncthreads();
    int buf = 0;

    for (int kt = 0; kt < NPTS / 2; kt += 64) {
        // issue next stage first: a full body of latency cover before the
        // barrier's vmcnt(0) drain
        if (kt + 64 < NPTS / 2) {
            int nb = buf ^ 1;
            __builtin_amdgcn_global_load_lds((const GLOBAL_AS void*)Ks,
                (LDS_AS void*)&Klds[nb][(16 * w) * 64], 16, 0, 0);
            __builtin_amdgcn_global_load_lds((const GLOBAL_AS void*)(Ks + 8 * HDIM),
                (LDS_AS void*)&Klds[nb][(16 * w + 8) * 64], 16, 0, 0);
            __builtin_amdgcn_global_load_lds((const GLOBAL_AS void*)Vs0,
                (LDS_AS void*)&Vlds[nb][(16 * w) * 64], 16, 0, 0);
            __builtin_amdgcn_global_load_lds((const GLOBAL_AS void*)Vs1,
                (LDS_AS void*)&Vlds[nb][(16 * w + 8) * 64], 16, 0, 0);
            Ks += 64 * HDIM; Vs0 += 64; Vs1 += 64;
        }

        // K A-frags from LDS
        bf16x8 kf[4][2];
        #pragma unroll
        for (int kn = 0; kn < 4; ++kn) {
            kf[kn][0] = *(const bf16x8*)&Klds[buf][1024 * kn + koff0];
            kf[kn][1] = *(const bf16x8*)&Klds[buf][1024 * kn + koff1];
        }

        // V A-frags te=0,1 issued EARLY: these have no dependence on QK, so
        // their LDS-read time drains underneath the QK MFMA burst instead of
        // serializing after softmax (the measured phase-lock cost).
        bf16x8 vf0[2][2];
        #pragma unroll
        for (int te = 0; te < 2; ++te) {
            vf0[te][0] = *(const bf16x8*)&Vlds[buf][1024 * te + koff0];
            vf0[te][1] = *(const bf16x8*)&Vlds[buf][1024 * te + koff1];
        }

        // S^T = K Q^T : st[kn][m], row=key(quad*4+r), col=qrow(l15)
        f32x4 st[4][2];
        #pragma unroll
        for (int kn = 0; kn < 4; ++kn)
            #pragma unroll
            for (int m = 0; m < 2; ++m) st[kn][m] = (f32x4){0.f, 0.f, 0.f, 0.f};
        #pragma unroll
        for (int kn = 0; kn < 4; ++kn)
            #pragma unroll
            for (int m = 0; m < 2; ++m) {
                st[kn][m] = __builtin_amdgcn_mfma_f32_16x16x32_bf16(
                    kf[kn][0], qf[m][0], st[kn][m], 0, 0, 0);
                st[kn][m] = __builtin_amdgcn_mfma_f32_16x16x32_bf16(
                    kf[kn][1], qf[m][1], st[kn][m], 0, 0, 0);
            }

        // max-free softmax in registers: pt = bf16 exp2(S^T), packed cvt
        bf16x8 pt[2][2];
        #pragma unroll
        for (int kb = 0; kb < 2; ++kb)
            #pragma unroll
            for (int m = 0; m < 2; ++m) {
                float a0 = EXP2F(st[2 * kb + 0][m][0]);
                float a1 = EXP2F(st[2 * kb + 0][m][1]);
                float a2 = EXP2F(st[2 * kb + 0][m][2]);
                float a3 = EXP2F(st[2 * kb + 0][m][3]);
                float b0 = EXP2F(st[2 * kb + 1][m][0]);
                float b1 = EXP2F(st[2 * kb + 1][m][1]);
                float b2 = EXP2F(st[2 * kb + 1][m][2]);
                float b3 = EXP2F(st[2 * kb + 1][m][3]);
                union { uint4 u; bf16x8 v; } uu;
                uu.u.x = pk2bf(a0, a1);
                uu.u.y = pk2bf(a2, a3);
                uu.u.z = pk2bf(b0, b1);
                uu.u.w = pk2bf(b2, b3);
                pt[kb][m] = uu.v;
            }

        // V A-frags te=2,3 issued here: drain under Lacc + PV-te01 MFMAs
        bf16x8 vf1[2][2];
        #pragma unroll
        for (int te = 0; te < 2; ++te) {
            vf1[te][0] = *(const bf16x8*)&Vlds[buf][1024 * (te + 2) + koff0];
            vf1[te][1] = *(const bf16x8*)&Vlds[buf][1024 * (te + 2) + koff1];
        }

        // row-sum in the matrix pipe: Lacc[m] += ones x pt (all rows equal l)
        #pragma unroll
        for (int kb = 0; kb < 2; ++kb)
            #pragma unroll
            for (int m = 0; m < 2; ++m)
                Lacc[m] = __builtin_amdgcn_mfma_f32_16x16x32_bf16(
                    ones, pt[kb][m], Lacc[m], 0, 0, 0);

        // O^T += V^T P^T  (pure register path); te01 first (vf0 ready),
        // te23 last (vf1 reads covered by the MFMAs above)
        #pragma unroll
        for (int te = 0; te < 2; ++te)
            #pragma unroll
            for (int m = 0; m < 2; ++m) {
                OT[te][m] = __builtin_amdgcn_mfma_f32_16x16x32_bf16(
                    vf0[te][0], pt[0][m], OT[te][m], 0, 0, 0);
                OT[te][m] = __builtin_amdgcn_mfma_f32_16x16x32_bf16(
                    vf0[te][1], pt[1][m], OT[te][m], 0, 0, 0);
            }
        #pragma unroll
        for (int te = 0; te < 2; ++te)
            #pragma unroll
            for (int m = 0; m < 2; ++m) {
                OT[te + 2][m] = __builtin_amdgcn_mfma_f32_16x16x32_bf16(
                    vf1[te][0], pt[0][m], OT[te + 2][m], 0, 0, 0);
                OT[te + 2][m] = __builtin_amdgcn_mfma_f32_16x16x32_bf16(
                    vf1[te][1], pt[1][m], OT[te + 2][m], 0, 0, 0);
            }

        __syncthreads();   // Klds/Vlds[buf] reads done; next stage visible
        buf ^= 1;
    }

    // epilogue: l comes straight out of Lacc (all components/quads equal);
    // write unnormalized O^T packed
    #pragma unroll
    for (int m = 0; m < 2; ++m) {
        int n = q0 + 32 * w + 16 * m + l15;
        if (quad == 0) lp[n] = Lacc[m][0];
        #pragma unroll
        for (int te = 0; te < 4; ++te) {
            uint2 pk;
            pk.x = pk2bf(OT[te][m][0], OT[te][m][1]);
            pk.y = pk2bf(OT[te][m][2], OT[te][m][3]);
            *(uint2*)&op[(size_t)n * DIM + h * HDIM + 16 * te + quad * 4] = pk;
        }
    }
}

// ---------------------------------------------------------------------------
// Merge k-split partials: op0 <- bf16((op0 + op1) / (l0 + l1))  in place.
// ---------------------------------------------------------------------------
__global__ __launch_bounds__(256) void reduce_kernel(
    unsigned short* __restrict__ op0, const unsigned short* __restrict__ op1,
    const float* __restrict__ l0, const float* __restrict__ l1)
{
    int gid = blockIdx.x * 256 + threadIdx.x;   // over N*DIM/4
    int n  = gid >> 7;
    int c4 = gid & 127;
    int h  = c4 >> 4;
    float inv = 1.0f / (l0[h * NPTS + n] + l1[h * NPTS + n]);
    ushort4 a = *(const ushort4*)&op0[(size_t)gid * 4];
    ushort4 b = *(const ushort4*)&op1[(size_t)gid * 4];
    uint2 o;
    o.x = pk2bf((bf2f(a.x) + bf2f(b.x)) * inv, (bf2f(a.y) + bf2f(b.y)) * inv);
    o.y = pk2bf((bf2f(a.z) + bf2f(b.z)) * inv, (bf2f(a.w) + bf2f(b.w)) * inv);
    *(uint2*)&op0[(size_t)gid * 4] = o;
}

// ---------------------------------------------------------------------------
// Output projection, bf16 MFMA, direct-global frags.
// ---------------------------------------------------------------------------
__global__ __launch_bounds__(256) void out_mfma_kernel(
    const unsigned short* __restrict__ cc,    // [N][512] bf16 normalized heads
    const unsigned short* __restrict__ wot,   // [512][512] bf16 [e_out][k]
    const float* __restrict__ bo, const float* __restrict__ x,
    float* __restrict__ outp)
{
    const int t = threadIdx.x, w = t >> 6, lane = t & 63;
    const int l15 = lane & 15, quad = lane >> 4;
    const int r0 = blockIdx.x * 128 + w * 32;
    const int c0 = blockIdx.y * 64;

    f32x4 O[2][4];
    #pragma unroll
    for (int mt = 0; mt < 2; ++mt)
        #pragma unroll
        for (int tn = 0; tn < 4; ++tn) O[mt][tn] = (f32x4){0.f, 0.f, 0.f, 0.f};

    for (int k0 = 0; k0 < DIM; k0 += 64) {
        bf16x8 af[2][2], bf[4][2];
        #pragma unroll
        for (int mt = 0; mt < 2; ++mt)
            #pragma unroll
            for (int kc = 0; kc < 2; ++kc)
                af[mt][kc] = *(const bf16x8*)
                    &cc[(size_t)(r0 + 16 * mt + l15) * DIM + k0 + quad * 8 + 32 * kc];
        #pragma unroll
        for (int tn = 0; tn < 4; ++tn)
            #pragma unroll
            for (int kc = 0; kc < 2; ++kc)
                bf[tn][kc] = *(const bf16x8*)
                    &wot[(size_t)(c0 + l15 + 16 * tn) * DIM + k0 + quad * 8 + 32 * kc];
        #pragma unroll
        for (int mt = 0; mt < 2; ++mt)
            #pragma unroll
            for (int tn = 0; tn < 4; ++tn) {
                O[mt][tn] = __builtin_amdgcn_mfma_f32_16x16x32_bf16(
                    af[mt][0], bf[tn][0], O[mt][tn], 0, 0, 0);
                O[mt][tn] = __builtin_amdgcn_mfma_f32_16x16x32_bf16(
                    af[mt][1], bf[tn][1], O[mt][tn], 0, 0, 0);
            }
    }

    #pragma unroll
    for (int mt = 0; mt < 2; ++mt)
        #pragma unroll
        for (int tn = 0; tn < 4; ++tn) {
            int e = c0 + l15 + 16 * tn;
            float be = bo[e];
            #pragma unroll
            for (int r = 0; r < 4; ++r) {
                int n = r0 + 16 * mt + quad * 4 + r;
                outp[(size_t)n * DIM + e] = O[mt][tn][r] + be + x[(size_t)n * DIM + e];
            }
        }
}

extern "C" void kernel_launch(void* const* d_in, const int* in_sizes, int n_in,
                              void* d_out, int out_size, void* d_ws, size_t ws_size,
                              hipStream_t stream) {
    const float* x  = (const float*)d_in[0];
    const float* Wq = (const float*)d_in[1];
    const float* bq = (const float*)d_in[2];
    const float* Wk = (const float*)d_in[3];
    const float* bk = (const float*)d_in[4];
    const float* Wv = (const float*)d_in[5];
    const float* bv = (const float*)d_in[6];
    const float* Wo = (const float*)d_in[7];
    const float* bo = (const float*)d_in[8];
    float* out = (float*)d_out;

    const size_t per = (size_t)NHEAD * NPTS * HDIM;            // 4M elems
    unsigned short* xbf   = (unsigned short*)d_ws;             //  8 MB
    unsigned short* wtq   = xbf + (size_t)NPTS * DIM;          //  1.5 MB
    unsigned short* wot   = wtq + (size_t)24 * HDIM * DIM;     //  0.5 MB
    unsigned short* q_bf  = wot + (size_t)DIM * DIM;           //  8 MB
    unsigned short* k_bf  = q_bf + per;                        //  8 MB
    unsigned short* vt_bf = k_bf + per;                        //  8 MB
    unsigned short* op0   = vt_bf + per;                       //  8 MB
    unsigned short* op1   = op0 + (size_t)NPTS * DIM;          //  8 MB
    float*          lpart = (float*)(op1 + (size_t)NPTS * DIM); // 512 KB
    // total ws: ~50.5 MB

    cvt_x_kernel<<<dim3(NPTS * DIM / 8 / 256), 256, 0, stream>>>(x, xbf);
    tr_w_kernel<<<dim3(8, 1, 24), 256, 0, stream>>>(Wq, Wk, Wv, wtq);
    tr_wo_kernel<<<dim3(8, 8), 256, 0, stream>>>(Wo, wot);
    qkv_mfma_kernel<<<dim3(NPTS / 128, 24), 256, 0, stream>>>(
        xbf, wtq, bq, bk, bv, q_bf, k_bf, vt_bf);
    attn_kernel<<<dim3(NPTS / 128, NHEAD, 2), 256, 0, stream>>>(
        q_bf, k_bf, vt_bf, op0, lpart);
    reduce_kernel<<<dim3(NPTS * DIM / 4 / 256), 256, 0, stream>>>(
        op0, op1, lpart, lpart + (size_t)NHEAD * NPTS);
    out_mfma_kernel<<<dim3(NPTS / 128, DIM / 64), 256, 0, stream>>>(
        op0, wot, bo, x, out);
}

// Round 10
// 330.464 us; speedup vs baseline: 1.1474x; 1.0613x over previous
//
#include <hip/hip_runtime.h>
#include <hip/hip_bf16.h>

#define NPTS 8192
#define DIM  512
#define NHEAD 8
#define HDIM 64

typedef short bf16x8 __attribute__((ext_vector_type(8)));   // 8 bf16 = 4 VGPRs
typedef float f32x4  __attribute__((ext_vector_type(4)));   // MFMA C/D

#define GLOBAL_AS __attribute__((address_space(1)))
#define LDS_AS    __attribute__((address_space(3)))

#if __has_builtin(__builtin_amdgcn_exp2f)
#define EXP2F(x) __builtin_amdgcn_exp2f(x)
#else
#define EXP2F(x) __expf((x) * 0.6931471805599453f)
#endif

// fp32 -> bf16 round-nearest-even (scalar)
__device__ __forceinline__ unsigned short f2bf(float f) {
    union { float f; unsigned int u; } v; v.f = f;
    unsigned int r = v.u + 0x7FFFu + ((v.u >> 16) & 1u);
    return (unsigned short)(r >> 16);
}
__device__ __forceinline__ float bf2f(unsigned short u) {
    union { unsigned int i; float f; } v; v.i = ((unsigned int)u) << 16;
    return v.f;
}
// packed 2x f32 -> bf16 pair (v_cvt_pk_bf16_f32 on gfx950)
__device__ __forceinline__ unsigned int pk2bf(float a, float b) {
    __hip_bfloat162 h = __float22bfloat162_rn(float2{a, b});
    union { __hip_bfloat162 h; unsigned int u; } v; v.h = h;
    return v.u;
}

// ---------------------------------------------------------------------------
// Prep 1: x fp32 -> bf16
// ---------------------------------------------------------------------------
__global__ __launch_bounds__(256) void cvt_x_kernel(
    const float* __restrict__ in, unsigned short* __restrict__ outp)
{
    int gid = blockIdx.x * 256 + threadIdx.x;   // over N*DIM/8
    float4 a = ((const float4*)in)[gid * 2];
    float4 b = ((const float4*)in)[gid * 2 + 1];
    uint4 u;
    u.x = pk2bf(a.x, a.y); u.y = pk2bf(a.z, a.w);
    u.z = pk2bf(b.x, b.y); u.w = pk2bf(b.z, b.w);
    ((uint4*)outp)[gid] = u;
}

// ---------------------------------------------------------------------------
// Prep 2: Wq/Wk/Wv [h][512][64] fp32 -> wtq [zh][64][512] bf16 (transposed)
// ---------------------------------------------------------------------------
__global__ __launch_bounds__(256) void tr_w_kernel(
    const float* __restrict__ Wq, const float* __restrict__ Wk,
    const float* __restrict__ Wv, unsigned short* __restrict__ wtq)
{
    int zh = blockIdx.z, z = zh >> 3, h = zh & 7;
    const float* src = (z == 0 ? Wq : z == 1 ? Wk : Wv) + (size_t)h * DIM * HDIM;
    unsigned short* dst = wtq + (size_t)zh * HDIM * DIM;
    int k0 = blockIdx.x * 64;
    __shared__ float tile[64][65];
    int t = threadIdx.x, c = t & 63, r = t >> 6;
    #pragma unroll
    for (int i = 0; i < 16; ++i)
        tile[r + 4 * i][c] = src[(size_t)(k0 + r + 4 * i) * HDIM + c];
    __syncthreads();
    #pragma unroll
    for (int i = 0; i < 16; ++i)
        dst[(size_t)(r + 4 * i) * DIM + k0 + c] = f2bf(tile[c][r + 4 * i]);
}

// ---------------------------------------------------------------------------
// Prep 3: Wo [512][512] fp32 -> wot [512][512] bf16 transposed ([e_out][k])
// ---------------------------------------------------------------------------
__global__ __launch_bounds__(256) void tr_wo_kernel(
    const float* __restrict__ Wo, unsigned short* __restrict__ wot)
{
    int k0 = blockIdx.x * 64, e0 = blockIdx.y * 64;
    __shared__ float tile[64][65];
    int t = threadIdx.x, c = t & 63, r = t >> 6;
    #pragma unroll
    for (int i = 0; i < 16; ++i)
        tile[r + 4 * i][c] = Wo[(size_t)(k0 + r + 4 * i) * DIM + e0 + c];
    __syncthreads();
    #pragma unroll
    for (int i = 0; i < 16; ++i)
        wot[(size_t)(e0 + r + 4 * i) * DIM + k0 + c] = f2bf(tile[c][r + 4 * i]);
}

// ---------------------------------------------------------------------------
// QKV projection, bf16 MFMA, direct-global frags.
//   z=0: q_bf[h][n][e]  (scale*log2e folded)   z=1: k_bf[h][n][e]
//   z=2: vtp[h][e][pi(n)] = V^T with the PV sigma-permutation pre-applied
//        within each 32-key block (pos = 8*quad + 4*mt + r holds
//        key = 16*mt + 4*quad + r) -- matches P^T's B-frag key order.
// ---------------------------------------------------------------------------
__global__ __launch_bounds__(256) void qkv_mfma_kernel(
    const unsigned short* __restrict__ xbf,   // [N][512] bf16
    const unsigned short* __restrict__ wtq,   // [24][64][512] bf16
    const float* __restrict__ bq, const float* __restrict__ bk,
    const float* __restrict__ bv,
    unsigned short* __restrict__ q_bf, unsigned short* __restrict__ k_bf,
    unsigned short* __restrict__ vt_bf)
{
    const int zh = blockIdx.y, z = zh >> 3, h = zh & 7;
    const unsigned short* W = wtq + (size_t)zh * HDIM * DIM;
    const float* b = (z == 0 ? bq : z == 1 ? bk : bv) + h * HDIM;
    const int t = threadIdx.x, w = t >> 6, lane = t & 63;
    const int l15 = lane & 15, quad = lane >> 4;
    const int r0 = blockIdx.x * 128 + w * 32;

    f32x4 O[2][4];
    #pragma unroll
    for (int mt = 0; mt < 2; ++mt)
        #pragma unroll
        for (int tn = 0; tn < 4; ++tn) O[mt][tn] = (f32x4){0.f, 0.f, 0.f, 0.f};

    for (int k0 = 0; k0 < DIM; k0 += 64) {
        bf16x8 af[2][2], bf[4][2];
        #pragma unroll
        for (int mt = 0; mt < 2; ++mt)
            #pragma unroll
            for (int kc = 0; kc < 2; ++kc)
                af[mt][kc] = *(const bf16x8*)
                    &xbf[(size_t)(r0 + 16 * mt + l15) * DIM + k0 + quad * 8 + 32 * kc];
        #pragma unroll
        for (int tn = 0; tn < 4; ++tn)
            #pragma unroll
            for (int kc = 0; kc < 2; ++kc)
                bf[tn][kc] = *(const bf16x8*)
                    &W[(size_t)(l15 + 16 * tn) * DIM + k0 + quad * 8 + 32 * kc];
        #pragma unroll
        for (int mt = 0; mt < 2; ++mt)
            #pragma unroll
            for (int tn = 0; tn < 4; ++tn) {
                O[mt][tn] = __builtin_amdgcn_mfma_f32_16x16x32_bf16(
                    af[mt][0], bf[tn][0], O[mt][tn], 0, 0, 0);
                O[mt][tn] = __builtin_amdgcn_mfma_f32_16x16x32_bf16(
                    af[mt][1], bf[tn][1], O[mt][tn], 0, 0, 0);
            }
    }

    if (z < 2) {
        unsigned short* outp = (z == 0 ? q_bf : k_bf) + (size_t)h * NPTS * HDIM;
        const float sc = (z == 0) ? 0.18033688011112042f : 1.0f;  // 0.125*log2e | 1
        #pragma unroll
        for (int mt = 0; mt < 2; ++mt)
            #pragma unroll
            for (int tn = 0; tn < 4; ++tn) {
                int e = l15 + 16 * tn;
                float be = b[e];
                #pragma unroll
                for (int r = 0; r < 4; ++r) {
                    int n = r0 + 16 * mt + quad * 4 + r;
                    outp[(size_t)n * HDIM + e] = f2bf((O[mt][tn][r] + be) * sc);
                }
            }
    } else {
        unsigned short* vt = vt_bf + (size_t)h * HDIM * NPTS;
        #pragma unroll
        for (int mt = 0; mt < 2; ++mt)
            #pragma unroll
            for (int tn = 0; tn < 4; ++tn) {
                int e = l15 + 16 * tn;
                float be = b[e];
                uint2 pk;
                pk.x = pk2bf(O[mt][tn][0] + be, O[mt][tn][1] + be);
                pk.y = pk2bf(O[mt][tn][2] + be, O[mt][tn][3] + be);
                // sigma-permuted position within this 32-row block
                *(uint2*)&vt[(size_t)e * NPTS + r0 + quad * 8 + mt * 4] = pk;
            }
    }
}

// ---------------------------------------------------------------------------
// MFMA flash attention, R14b (R14 algorithm, lexically restructured after two
// infra failures -- the R12->R12b recovery recipe): 64 q-rows/wave with
// 64-key double-buffered tiles (32 KB LDS).
// Rationale: LDS pipe is the largest per-CU cost (~55%: every wave reads the
// whole 16 KB K/V tile, amortized over only 32 q-rows). This config halves
// LDS reads + barriers per unit work while keeping 2 blocks/CU residency
// (grid 512, 8 waves/CU -- same as R13). Techniques kept:
//   - sub-phase QK (two 32-key subphases; st transient 32 regs) [R11]
//   - vf te01 between subphases, te23 after softmax (cross-pipe overlap) [R13]
//   - ones-MFMA row-sum in the matrix pipe [R12]
//   - Z0-seeded st, hoisted constant-stride staging pointers [R12]
// Spill sentinel: WRITE_SIZE must stay ~16.9 MB, VGPR < 256.
// ---------------------------------------------------------------------------
#define STAGE_TILE(B)                                                         \
    do {                                                                      \
        __builtin_amdgcn_global_load_lds((const GLOBAL_AS void*)Kp,           \
            (LDS_AS void*)&Klds[B][(16 * w) * 64], 16, 0, 0);                 \
        __builtin_amdgcn_global_load_lds((const GLOBAL_AS void*)(Kp + 8 * HDIM), \
            (LDS_AS void*)&Klds[B][(16 * w + 8) * 64], 16, 0, 0);             \
        __builtin_amdgcn_global_load_lds((const GLOBAL_AS void*)Vp0,          \
            (LDS_AS void*)&Vlds[B][(16 * w) * 64], 16, 0, 0);                 \
        __builtin_amdgcn_global_load_lds((const GLOBAL_AS void*)Vp1,          \
            (LDS_AS void*)&Vlds[B][(16 * w + 8) * 64], 16, 0, 0);             \
        Kp += 64 * HDIM; Vp0 += 64; Vp1 += 64;                                \
    } while (0)

__global__ __launch_bounds__(256) void attn_kernel(
    const unsigned short* __restrict__ qg,   // [H][N][64] bf16, pre-scaled
    const unsigned short* __restrict__ kg,   // [H][N][64] bf16
    const unsigned short* __restrict__ vtg,  // [H][64][N] bf16, sigma-permuted
    unsigned short* __restrict__ opart,      // [2][N][DIM] bf16 unnormalized
    float* __restrict__ lpart)               // [2][H][N] fp32
{
    const int h  = blockIdx.y;
    const int ks = blockIdx.z;
    const int q0 = blockIdx.x * 256;
    const int kbase = ks * (NPTS / 2);
    const unsigned short* Q  = qg  + (size_t)h * NPTS * HDIM;
    const unsigned short* K  = kg  + (size_t)h * NPTS * HDIM;
    const unsigned short* Vt = vtg + (size_t)h * HDIM * NPTS;
    unsigned short* op = opart + (size_t)ks * NPTS * DIM;
    float* lp = lpart + (size_t)(ks * NHEAD + h) * NPTS;

    __shared__ __align__(16) unsigned short Klds[2][64 * 64];  // 16 KB
    __shared__ __align__(16) unsigned short Vlds[2][64 * 64];  // 16 KB

    const int t    = threadIdx.x;
    const int w    = t >> 6;
    const int lane = t & 63;
    const int l15  = lane & 15;
    const int quad = lane >> 4;

    const int koff0 = l15 * 64 + (quad ^ (l15 & 7)) * 8;
    const int koff1 = koff0 ^ 32;

    const int srow   = lane >> 3;
    const int schunk = (lane & 7) ^ srow;

    // Q B-frags: 4 m-tiles of 16 rows -> 64 q-rows per wave
    bf16x8 qf[4][2];
    #pragma unroll
    for (int m = 0; m < 4; ++m)
        #pragma unroll
        for (int kc = 0; kc < 2; ++kc)
            qf[m][kc] = *(const bf16x8*)
                &Q[(size_t)(q0 + 64 * w + 16 * m + l15) * HDIM + quad * 8 + 32 * kc];

    // all-ones bf16 A-frag for the row-sum MFMA (0x3F80 == bf16 1.0)
    const bf16x8 ones = {(short)0x3F80, (short)0x3F80, (short)0x3F80,
                         (short)0x3F80, (short)0x3F80, (short)0x3F80,
                         (short)0x3F80, (short)0x3F80};
    // persistent zero C-in: seeds each st accumulation without fresh movs
    const f32x4 Z0 = (f32x4){0.f, 0.f, 0.f, 0.f};

    // O^T accumulators [te][m]: row=quad*4+r -> e, col=l15 -> qrow
    f32x4 OT[4][4];
    f32x4 Lacc[4];
    #pragma unroll
    for (int te = 0; te < 4; ++te)
        #pragma unroll
        for (int m = 0; m < 4; ++m) OT[te][m] = (f32x4){0.f, 0.f, 0.f, 0.f};
    #pragma unroll
    for (int m = 0; m < 4; ++m) Lacc[m] = (f32x4){0.f, 0.f, 0.f, 0.f};

    // running staging pointers (advanced by constant strides inside STAGE_TILE)
    const unsigned short* Kp  = K  + (size_t)(kbase + 16 * w + srow) * HDIM
                                   + schunk * 8;
    const unsigned short* Vp0 = Vt + (size_t)(16 * w + srow) * NPTS
                                   + kbase + schunk * 8;
    const unsigned short* Vp1 = Vp0 + (size_t)8 * NPTS;

    STAGE_TILE(0);
    __syncthreads();
    int buf = 0;

    for (int kt = 0; kt < NPTS / 2; kt += 64) {
        // issue next stage first: a full body of latency cover before the
        // barrier's vmcnt(0) drain
        if (kt + 64 < NPTS / 2) {
            const int nxt = buf ^ 1;
            if (nxt) STAGE_TILE(1); else STAGE_TILE(0);
        }

        bf16x8 pt[2][4];

        // ---- subphase kb=0: keys 0..31 of the tile (kn slots 0,1) ----
        {
            bf16x8 kf[2][2];
            #pragma unroll
            for (int kn = 0; kn < 2; ++kn) {
                kf[kn][0] = *(const bf16x8*)&Klds[buf][1024 * kn + koff0];
                kf[kn][1] = *(const bf16x8*)&Klds[buf][1024 * kn + koff1];
            }
            f32x4 st[2][4];
            #pragma unroll
            for (int kn = 0; kn < 2; ++kn)
                #pragma unroll
                for (int m = 0; m < 4; ++m) {
                    st[kn][m] = __builtin_amdgcn_mfma_f32_16x16x32_bf16(
                        kf[kn][0], qf[m][0], Z0, 0, 0, 0);
                    st[kn][m] = __builtin_amdgcn_mfma_f32_16x16x32_bf16(
                        kf[kn][1], qf[m][1], st[kn][m], 0, 0, 0);
                }
            #pragma unroll
            for (int m = 0; m < 4; ++m) {
                float e0 = EXP2F(st[0][m][0]);
                float e1 = EXP2F(st[0][m][1]);
                float e2 = EXP2F(st[0][m][2]);
                float e3 = EXP2F(st[0][m][3]);
                float e4 = EXP2F(st[1][m][0]);
                float e5 = EXP2F(st[1][m][1]);
                float e6 = EXP2F(st[1][m][2]);
                float e7 = EXP2F(st[1][m][3]);
                union { uint4 u; bf16x8 v; } uu;
                uu.u.x = pk2bf(e0, e1);
                uu.u.y = pk2bf(e2, e3);
                uu.u.z = pk2bf(e4, e5);
                uu.u.w = pk2bf(e6, e7);
                pt[0][m] = uu.v;
            }
        }

        // V A-frags te=0,1 issued here: LDS reads drain under the kb=1 QK
        // MFMA burst (R13 overlap lesson)
        bf16x8 vf0[2][2];
        #pragma unroll
        for (int te = 0; te < 2; ++te) {
            vf0[te][0] = *(const bf16x8*)&Vlds[buf][1024 * te + koff0];
            vf0[te][1] = *(const bf16x8*)&Vlds[buf][1024 * te + koff1];
        }

        // ---- subphase kb=1: keys 32..63 of the tile (kn slots 2,3) ----
        {
            bf16x8 kf[2][2];
            #pragma unroll
            for (int kn = 0; kn < 2; ++kn) {
                kf[kn][0] = *(const bf16x8*)&Klds[buf][1024 * (kn + 2) + koff0];
                kf[kn][1] = *(const bf16x8*)&Klds[buf][1024 * (kn + 2) + koff1];
            }
            f32x4 st[2][4];
            #pragma unroll
            for (int kn = 0; kn < 2; ++kn)
                #pragma unroll
                for (int m = 0; m < 4; ++m) {
                    st[kn][m] = __builtin_amdgcn_mfma_f32_16x16x32_bf16(
                        kf[kn][0], qf[m][0], Z0, 0, 0, 0);
                    st[kn][m] = __builtin_amdgcn_mfma_f32_16x16x32_bf16(
                        kf[kn][1], qf[m][1], st[kn][m], 0, 0, 0);
                }
            #pragma unroll
            for (int m = 0; m < 4; ++m) {
                float e0 = EXP2F(st[0][m][0]);
                float e1 = EXP2F(st[0][m][1]);
                float e2 = EXP2F(st[0][m][2]);
                float e3 = EXP2F(st[0][m][3]);
                float e4 = EXP2F(st[1][m][0]);
                float e5 = EXP2F(st[1][m][1]);
                float e6 = EXP2F(st[1][m][2]);
                float e7 = EXP2F(st[1][m][3]);
                union { uint4 u; bf16x8 v; } uu;
                uu.u.x = pk2bf(e0, e1);
                uu.u.y = pk2bf(e2, e3);
                uu.u.z = pk2bf(e4, e5);
                uu.u.w = pk2bf(e6, e7);
                pt[1][m] = uu.v;
            }
        }

        // V A-frags te=2,3: drain under Lacc + PV-te01 MFMAs
        bf16x8 vf1[2][2];
        #pragma unroll
        for (int te = 0; te < 2; ++te) {
            vf1[te][0] = *(const bf16x8*)&Vlds[buf][1024 * (te + 2) + koff0];
            vf1[te][1] = *(const bf16x8*)&Vlds[buf][1024 * (te + 2) + koff1];
        }

        // row-sum in the matrix pipe: Lacc[m] += ones x pt (all rows equal l)
        #pragma unroll
        for (int kb = 0; kb < 2; ++kb)
            #pragma unroll
            for (int m = 0; m < 4; ++m)
                Lacc[m] = __builtin_amdgcn_mfma_f32_16x16x32_bf16(
                    ones, pt[kb][m], Lacc[m], 0, 0, 0);

        // O^T += V^T P^T  (pure register path); te01 first (vf0 ready),
        // te23 last (vf1 reads covered by the MFMAs above)
        #pragma unroll
        for (int te = 0; te < 2; ++te)
            #pragma unroll
            for (int m = 0; m < 4; ++m) {
                OT[te][m] = __builtin_amdgcn_mfma_f32_16x16x32_bf16(
                    vf0[te][0], pt[0][m], OT[te][m], 0, 0, 0);
                OT[te][m] = __builtin_amdgcn_mfma_f32_16x16x32_bf16(
                    vf0[te][1], pt[1][m], OT[te][m], 0, 0, 0);
            }
        #pragma unroll
        for (int te = 0; te < 2; ++te)
            #pragma unroll
            for (int m = 0; m < 4; ++m) {
                OT[te + 2][m] = __builtin_amdgcn_mfma_f32_16x16x32_bf16(
                    vf1[te][0], pt[0][m], OT[te + 2][m], 0, 0, 0);
                OT[te + 2][m] = __builtin_amdgcn_mfma_f32_16x16x32_bf16(
                    vf1[te][1], pt[1][m], OT[te + 2][m], 0, 0, 0);
            }

        __syncthreads();   // Klds/Vlds[buf] reads done; next stage visible
        buf ^= 1;
    }

    // epilogue: l comes straight out of Lacc (all components/quads equal);
    // write unnormalized O^T packed
    #pragma unroll
    for (int m = 0; m < 4; ++m) {
        int n = q0 + 64 * w + 16 * m + l15;
        if (quad == 0) lp[n] = Lacc[m][0];
        #pragma unroll
        for (int te = 0; te < 4; ++te) {
            uint2 pk;
            pk.x = pk2bf(OT[te][m][0], OT[te][m][1]);
            pk.y = pk2bf(OT[te][m][2], OT[te][m][3]);
            *(uint2*)&op[(size_t)n * DIM + h * HDIM + 16 * te + quad * 4] = pk;
        }
    }
}

// ---------------------------------------------------------------------------
// Merge k-split partials: op0 <- bf16((op0 + op1) / (l0 + l1))  in place.
// ---------------------------------------------------------------------------
__global__ __launch_bounds__(256) void reduce_kernel(
    unsigned short* __restrict__ op0, const unsigned short* __restrict__ op1,
    const float* __restrict__ l0, const float* __restrict__ l1)
{
    int gid = blockIdx.x * 256 + threadIdx.x;   // over N*DIM/4
    int n  = gid >> 7;
    int c4 = gid & 127;
    int h  = c4 >> 4;
    float inv = 1.0f / (l0[h * NPTS + n] + l1[h * NPTS + n]);
    ushort4 a = *(const ushort4*)&op0[(size_t)gid * 4];
    ushort4 b = *(const ushort4*)&op1[(size_t)gid * 4];
    uint2 o;
    o.x = pk2bf((bf2f(a.x) + bf2f(b.x)) * inv, (bf2f(a.y) + bf2f(b.y)) * inv);
    o.y = pk2bf((bf2f(a.z) + bf2f(b.z)) * inv, (bf2f(a.w) + bf2f(b.w)) * inv);
    *(uint2*)&op0[(size_t)gid * 4] = o;
}

// ---------------------------------------------------------------------------
// Output projection, bf16 MFMA, direct-global frags.
// ---------------------------------------------------------------------------
__global__ __launch_bounds__(256) void out_mfma_kernel(
    const unsigned short* __restrict__ cc,    // [N][512] bf16 normalized heads
    const unsigned short* __restrict__ wot,   // [512][512] bf16 [e_out][k]
    const float* __restrict__ bo, const float* __restrict__ x,
    float* __restrict__ outp)
{
    const int t = threadIdx.x, w = t >> 6, lane = t & 63;
    const int l15 = lane & 15, quad = lane >> 4;
    const int r0 = blockIdx.x * 128 + w * 32;
    const int c0 = blockIdx.y * 64;

    f32x4 O[2][4];
    #pragma unroll
    for (int mt = 0; mt < 2; ++mt)
        #pragma unroll
        for (int tn = 0; tn < 4; ++tn) O[mt][tn] = (f32x4){0.f, 0.f, 0.f, 0.f};

    for (int k0 = 0; k0 < DIM; k0 += 64) {
        bf16x8 af[2][2], bf[4][2];
        #pragma unroll
        for (int mt = 0; mt < 2; ++mt)
            #pragma unroll
            for (int kc = 0; kc < 2; ++kc)
                af[mt][kc] = *(const bf16x8*)
                    &cc[(size_t)(r0 + 16 * mt + l15) * DIM + k0 + quad * 8 + 32 * kc];
        #pragma unroll
        for (int tn = 0; tn < 4; ++tn)
            #pragma unroll
            for (int kc = 0; kc < 2; ++kc)
                bf[tn][kc] = *(const bf16x8*)
                    &wot[(size_t)(c0 + l15 + 16 * tn) * DIM + k0 + quad * 8 + 32 * kc];
        #pragma unroll
        for (int mt = 0; mt < 2; ++mt)
            #pragma unroll
            for (int tn = 0; tn < 4; ++tn) {
                O[mt][tn] = __builtin_amdgcn_mfma_f32_16x16x32_bf16(
                    af[mt][0], bf[tn][0], O[mt][tn], 0, 0, 0);
                O[mt][tn] = __builtin_amdgcn_mfma_f32_16x16x32_bf16(
                    af[mt][1], bf[tn][1], O[mt][tn], 0, 0, 0);
            }
    }

    #pragma unroll
    for (int mt = 0; mt < 2; ++mt)
        #pragma unroll
        for (int tn = 0; tn < 4; ++tn) {
            int e = c0 + l15 + 16 * tn;
            float be = bo[e];
            #pragma unroll
            for (int r = 0; r < 4; ++r) {
                int n = r0 + 16 * mt + quad * 4 + r;
                outp[(size_t)n * DIM + e] = O[mt][tn][r] + be + x[(size_t)n * DIM + e];
            }
        }
}

extern "C" void kernel_launch(void* const* d_in, const int* in_sizes, int n_in,
                              void* d_out, int out_size, void* d_ws, size_t ws_size,
                              hipStream_t stream) {
    const float* x  = (const float*)d_in[0];
    const float* Wq = (const float*)d_in[1];
    const float* bq = (const float*)d_in[2];
    const float* Wk = (const float*)d_in[3];
    const float* bk = (const float*)d_in[4];
    const float* Wv = (const float*)d_in[5];
    const float* bv = (const float*)d_in[6];
    const float* Wo = (const float*)d_in[7];
    const float* bo = (const float*)d_in[8];
    float* out = (float*)d_out;

    const size_t per = (size_t)NHEAD * NPTS * HDIM;            // 4M elems
    unsigned short* xbf   = (unsigned short*)d_ws;             //  8 MB
    unsigned short* wtq   = xbf + (size_t)NPTS * DIM;          //  1.5 MB
    unsigned short* wot   = wtq + (size_t)24 * HDIM * DIM;     //  0.5 MB
    unsigned short* q_bf  = wot + (size_t)DIM * DIM;           //  8 MB
    unsigned short* k_bf  = q_bf + per;                        //  8 MB
    unsigned short* vt_bf = k_bf + per;                        //  8 MB
    unsigned short* op0   = vt_bf + per;                       //  8 MB
    unsigned short* op1   = op0 + (size_t)NPTS * DIM;          //  8 MB
    float*          lpart = (float*)(op1 + (size_t)NPTS * DIM); // 512 KB
    // total ws: ~50.5 MB

    cvt_x_kernel<<<dim3(NPTS * DIM / 8 / 256), 256, 0, stream>>>(x, xbf);
    tr_w_kernel<<<dim3(8, 1, 24), 256, 0, stream>>>(Wq, Wk, Wv, wtq);
    tr_wo_kernel<<<dim3(8, 8), 256, 0, stream>>>(Wo, wot);
    qkv_mfma_kernel<<<dim3(NPTS / 128, 24), 256, 0, stream>>>(
        xbf, wtq, bq, bk, bv, q_bf, k_bf, vt_bf);
    attn_kernel<<<dim3(NPTS / 256, NHEAD, 2), 256, 0, stream>>>(
        q_bf, k_bf, vt_bf, op0, lpart);
    reduce_kernel<<<dim3(NPTS * DIM / 4 / 256), 256, 0, stream>>>(
        op0, op1, lpart, lpart + (size_t)NHEAD * NPTS);
    out_mfma_kernel<<<dim3(NPTS / 128, DIM / 64), 256, 0, stream>>>(
        op0, wot, bo, x, out);
}